// Round 7
// baseline (4366.033 us; speedup 1.0000x reference)
//
#include <hip/hip_runtime.h>
#include <math.h>

// VisionMamba forward. Round 7: round-6 kernels (transposed x_dbl scan v3) with
// NO cross-kernel WAW aliasing: normed_bf and xdbl_t get disjoint buffers
// (round 6's union produced stale-read divergence after graph replays).
// Only alias kept: x_bf over xcbf+y_bf (round-4-validated, disjoint lifetime).
// B=64, L=196, D_MODEL=192, D_INNER=384, D_STATE=16, DT_RANK=12, DEPTH=24.

#define DEPTH 24
#define DM 192
#define DI 384
#define DS 16
#define DR 12
#define SEQL 196
#define BATCH 64
#define MROWS (BATCH*SEQL)   // 12544
#define XDP 8624             // x_dbl_t per-b plane: 44*196 floats

typedef unsigned short ushort_t;
typedef __bf16 bf16x8 __attribute__((ext_vector_type(8)));
typedef float f32x4 __attribute__((ext_vector_type(4)));

__device__ __forceinline__ float sigmoidf_(float x) { return 1.f / (1.f + __expf(-x)); }

__device__ __forceinline__ ushort_t f2bf(float f) {  // RNE fp32->bf16
    union { float f; unsigned u; } c; c.f = f;
    unsigned u = c.u;
    return (ushort_t)((u + 0x7FFFu + ((u >> 16) & 1u)) >> 16);
}
__device__ __forceinline__ float bf2f(ushort_t u) {
    union { unsigned u; float f; } c; c.u = ((unsigned)u) << 16;
    return c.f;
}

__device__ __forceinline__ void load_lds16(const ushort_t* g, ushort_t* l) {
    __builtin_amdgcn_global_load_lds((__attribute__((address_space(1))) void*)g,
                                     (__attribute__((address_space(3))) void*)l, 16, 0, 0);
}

// ---------------- fp32 -> bf16 bulk convert, 4 elems/thread ----------------
__global__ void f2bf4_kernel(const float* __restrict__ src, ushort_t* __restrict__ dst, int n4) {
    int i = blockIdx.x * 256 + threadIdx.x;
    if (i >= n4) return;
    float4 v = ((const float4*)src)[i];
    union { ushort_t s[4]; uint2 u; } o;
    o.s[0] = f2bf(v.x); o.s[1] = f2bf(v.y); o.s[2] = f2bf(v.z); o.s[3] = f2bf(v.w);
    ((uint2*)dst)[i] = o.u;
}

// xp_w [24][44][384] -> padded bf16 [24][64][384], rows 44..63 = 0
__global__ void xp_pad_kernel(const float* __restrict__ src, ushort_t* __restrict__ dst) {
    int i = blockIdx.x * 256 + threadIdx.x;
    if (i >= DEPTH * 64 * 384) return;
    int col = i % 384, row = (i / 384) & 63, d = i / (384 * 64);
    float v = (row < 44) ? src[(size_t)d * 44 * 384 + row * 384 + col] : 0.f;
    dst[i] = f2bf(v);
}

// ---------------- residual += hidden; out = LayerNorm(residual) ----------------
template<bool BF>
__global__ void ln_kernel(float* __restrict__ residual, const float* __restrict__ hidden,
                          const float* __restrict__ w, const float* __restrict__ b,
                          void* __restrict__ out_) {
    int wave = threadIdx.x >> 6, lane = threadIdx.x & 63;
    int row = blockIdx.x * 4 + wave;
    float* rr = residual + (size_t)row * DM;
    const float* hr = hidden + (size_t)row * DM;
    float v0 = rr[lane]       + hr[lane];
    float v1 = rr[lane + 64]  + hr[lane + 64];
    float v2 = rr[lane + 128] + hr[lane + 128];
    rr[lane] = v0; rr[lane + 64] = v1; rr[lane + 128] = v2;
    float s = v0 + v1 + v2;
    #pragma unroll
    for (int off = 32; off > 0; off >>= 1) s += __shfl_down(s, off);
    float mean = __shfl(s, 0) * (1.f / DM);
    float d0 = v0 - mean, d1 = v1 - mean, d2 = v2 - mean;
    float q = d0 * d0 + d1 * d1 + d2 * d2;
    #pragma unroll
    for (int off = 32; off > 0; off >>= 1) q += __shfl_down(q, off);
    float rstd = rsqrtf(__shfl(q, 0) * (1.f / DM) + 1e-5f);
    float o0 = d0 * rstd * w[lane]       + b[lane];
    float o1 = d1 * rstd * w[lane + 64]  + b[lane + 64];
    float o2 = d2 * rstd * w[lane + 128] + b[lane + 128];
    if constexpr (BF) {
        ushort_t* o = (ushort_t*)out_ + (size_t)row * DM;
        o[lane] = f2bf(o0); o[lane + 64] = f2bf(o1); o[lane + 128] = f2bf(o2);
    } else {
        float* o = (float*)out_ + (size_t)row * DM;
        o[lane] = o0; o[lane + 64] = o1; o[lane + 128] = o2;
    }
}

// ---------------- bf16 MFMA GEMM: C = A[M,K]bf16 * W[N,K]bf16^T ----------------
// BM=128. 4 waves, frag tiles FM x FN of 16x16, K-step 32. XOR-swizzled LDS slots.
// TC=false: C row-major [M, ldC], store col-tile only if tile idx < NST.
// TC=true : C transposed planes [b][col][196] (b = m/196, l = m%196), col<44 guard.
template<int BN, int WM, int WN, int NST, bool TC>
__global__ __launch_bounds__(256, 2) void gemm_mfma(const ushort_t* __restrict__ A,
        const ushort_t* __restrict__ W, float* __restrict__ C, int K, int ldC) {
    constexpr int FM = 128 / (WM * 16);
    constexpr int FN = BN / (WN * 16);
    __shared__ ushort_t sA[128 * 32];
    __shared__ ushort_t sB[BN * 32];
    const int t = threadIdx.x;
    const int wave = t >> 6, lane = t & 63;
    const int lr = lane & 15, lq = lane >> 4;
    const int wr = wave / WN, wc = wave % WN;
    const int m0 = blockIdx.x * 128, n0 = blockIdx.y * BN;
    const int wbase = t & ~63;

    f32x4 acc[FM][FN];
    #pragma unroll
    for (int i = 0; i < FM; i++)
        #pragma unroll
        for (int j = 0; j < FN; j++) acc[i][j] = f32x4{0.f, 0.f, 0.f, 0.f};

    for (int k0 = 0; k0 < K; k0 += 32) {
        __syncthreads();
        #pragma unroll
        for (int c = 0; c < 2; c++) {           // A: 512 slots
            int s = c * 256 + t;
            int row = s >> 2;
            int quad = (s & 3) ^ ((row >> 1) & 3);
            load_lds16(A + (size_t)(m0 + row) * K + k0 + quad * 8,
                       sA + (size_t)(c * 256 + wbase) * 8);
        }
        #pragma unroll
        for (int c = 0; c < BN * 4 / 256; c++) { // B: BN*4 slots
            int s = c * 256 + t;
            int row = s >> 2;
            int quad = (s & 3) ^ ((row >> 1) & 3);
            load_lds16(W + (size_t)(n0 + row) * K + k0 + quad * 8,
                       sB + (size_t)(c * 256 + wbase) * 8);
        }
        __syncthreads();
        bf16x8 af[FM], bfr[FN];
        #pragma unroll
        for (int i = 0; i < FM; i++) {
            int row = wr * FM * 16 + i * 16 + lr;
            int slot = (row << 2) | (lq ^ ((row >> 1) & 3));
            af[i] = *(const bf16x8*)&sA[(size_t)slot * 8];
        }
        #pragma unroll
        for (int j = 0; j < FN; j++) {
            int row = wc * FN * 16 + j * 16 + lr;
            int slot = (row << 2) | (lq ^ ((row >> 1) & 3));
            bfr[j] = *(const bf16x8*)&sB[(size_t)slot * 8];
        }
        #pragma unroll
        for (int i = 0; i < FM; i++)
            #pragma unroll
            for (int j = 0; j < FN; j++)
                acc[i][j] = __builtin_amdgcn_mfma_f32_16x16x32_bf16(af[i], bfr[j], acc[i][j], 0, 0, 0);
    }
    // C/D layout: col = lane&15, row = (lane>>4)*4 + reg
    int crow0 = m0 + wr * FM * 16 + lq * 4;
    int ccol0 = n0 + wc * FN * 16 + lr;
    if constexpr (TC) {
        #pragma unroll
        for (int i = 0; i < FM; i++) {
            int m = crow0 + i * 16;
            int bb = m / 196, l = m % 196;
            #pragma unroll
            for (int j = 0; j < FN; j++) {
                int col = ccol0 + j * 16;
                if (col < 44) {
                    float4 v = {acc[i][j][0], acc[i][j][1], acc[i][j][2], acc[i][j][3]};
                    *(float4*)(C + (size_t)bb * XDP + (size_t)col * 196 + l) = v;
                }
            }
        }
    } else {
        #pragma unroll
        for (int i = 0; i < FM; i++)
            #pragma unroll
            for (int j = 0; j < FN; j++) {
                if (wc * FN + j >= NST) continue;
                float* cp = C + (size_t)(crow0 + i * 16) * ldC + ccol0 + j * 16;
                #pragma unroll
                for (int r = 0; r < 4; r++) cp[(size_t)r * ldC] = acc[i][j][r];
            }
    }
}

// ---------------- Patch-embed bf16 MFMA with im2col A-loader ----------------
__global__ __launch_bounds__(256, 2) void gemm_patch_mfma(const ushort_t* __restrict__ Xbf,
        const ushort_t* __restrict__ Wbf, const float* __restrict__ bias, float* __restrict__ C) {
    constexpr int FM = 2, FN = 4;
    __shared__ ushort_t sA[128 * 32];
    __shared__ ushort_t sB[64 * 32];
    const int t = threadIdx.x;
    const int wave = t >> 6, lane = t & 63;
    const int lr = lane & 15, lq = lane >> 4;
    const int m0 = blockIdx.x * 128, n0 = blockIdx.y * 64;
    const int wbase = t & ~63;

    const ushort_t* abase[2];
    int aquad[2];
    #pragma unroll
    for (int c = 0; c < 2; c++) {
        int s = c * 256 + t;
        int row = s >> 2;
        aquad[c] = (s & 3) ^ ((row >> 1) & 3);
        int m = m0 + row;
        int b = m / 196, r = m % 196, py = r / 14, px = r % 14;
        abase[c] = Xbf + (size_t)b * 150528 + py * 3584 + px * 16;
    }
    int brow = t >> 2;
    int bquad = (t & 3) ^ ((brow >> 1) & 3);
    const ushort_t* bbase = Wbf + (size_t)(n0 + brow) * 768 + bquad * 8;

    f32x4 acc[FM][FN];
    #pragma unroll
    for (int i = 0; i < FM; i++)
        #pragma unroll
        for (int j = 0; j < FN; j++) acc[i][j] = f32x4{0.f, 0.f, 0.f, 0.f};

    for (int k0 = 0; k0 < 768; k0 += 32) {
        __syncthreads();
        #pragma unroll
        for (int c = 0; c < 2; c++) {
            int k = k0 + aquad[c] * 8;
            int ci = k >> 8, ky = (k >> 4) & 15, kx0 = k & 15;
            load_lds16(abase[c] + ci * 50176 + ky * 224 + kx0,
                       sA + (size_t)(c * 256 + wbase) * 8);
        }
        load_lds16(bbase + k0, sB + (size_t)wbase * 8);
        __syncthreads();
        bf16x8 af[FM], bfr[FN];
        #pragma unroll
        for (int i = 0; i < FM; i++) {
            int row = wave * FM * 16 + i * 16 + lr;
            int slot = (row << 2) | (lq ^ ((row >> 1) & 3));
            af[i] = *(const bf16x8*)&sA[(size_t)slot * 8];
        }
        #pragma unroll
        for (int j = 0; j < FN; j++) {
            int row = j * 16 + lr;
            int slot = (row << 2) | (lq ^ ((row >> 1) & 3));
            bfr[j] = *(const bf16x8*)&sB[(size_t)slot * 8];
        }
        #pragma unroll
        for (int i = 0; i < FM; i++)
            #pragma unroll
            for (int j = 0; j < FN; j++)
                acc[i][j] = __builtin_amdgcn_mfma_f32_16x16x32_bf16(af[i], bfr[j], acc[i][j], 0, 0, 0);
    }
    int crow0 = m0 + wave * FM * 16 + lq * 4;
    int ccol0 = n0 + lr;
    #pragma unroll
    for (int i = 0; i < FM; i++)
        #pragma unroll
        for (int j = 0; j < FN; j++) {
            int col = ccol0 + j * 16;
            float bv = bias[col];
            float* cp = C + (size_t)(crow0 + i * 16) * DM + col;
            #pragma unroll
            for (int r = 0; r < 4; r++) cp[(size_t)r * DM] = acc[i][j][r] + bv;
        }
}

// ---------------- Small fp32 GEMM (head only) ----------------
template<bool BIAS>
__global__ __launch_bounds__(256, 2) void gemm64(const float* __restrict__ A,
        const float* __restrict__ W, const float* __restrict__ bias,
        float* __restrict__ C, int M, int N, int K) {
    __shared__ float As[32][68];
    __shared__ float Ws[32][68];
    int t = threadIdx.x;
    int m0 = blockIdx.x * 64, n0 = blockIdx.y * 64;
    int lr = t >> 2, lk = (t & 3) * 4;
    int am = m0 + lr; bool avld = am < M;
    const float* Ap = A + (size_t)(avld ? am : 0) * K + lk;
    int wn = n0 + lr; bool wv = wn < N;
    const float* Wp = W + (size_t)(wv ? wn : 0) * K + lk;
    int tm = (t >> 4) * 4, tn = (t & 15) * 4;
    float acc[4][4];
    #pragma unroll
    for (int i = 0; i < 4; i++)
        #pragma unroll
        for (int j = 0; j < 4; j++) acc[i][j] = 0.f;

    for (int k0 = 0; k0 < K; k0 += 32) {
        float4 a0 = make_float4(0.f, 0.f, 0.f, 0.f), a1 = a0, w0 = a0, w1 = a0;
        if (avld) { a0 = *(const float4*)(Ap + k0); a1 = *(const float4*)(Ap + k0 + 16); }
        if (wv)   { w0 = *(const float4*)(Wp + k0); w1 = *(const float4*)(Wp + k0 + 16); }
        __syncthreads();
        As[lk + 0][lr] = a0.x; As[lk + 1][lr] = a0.y; As[lk + 2][lr] = a0.z; As[lk + 3][lr] = a0.w;
        As[lk + 16][lr] = a1.x; As[lk + 17][lr] = a1.y; As[lk + 18][lr] = a1.z; As[lk + 19][lr] = a1.w;
        Ws[lk + 0][lr] = w0.x; Ws[lk + 1][lr] = w0.y; Ws[lk + 2][lr] = w0.z; Ws[lk + 3][lr] = w0.w;
        Ws[lk + 16][lr] = w1.x; Ws[lk + 17][lr] = w1.y; Ws[lk + 18][lr] = w1.z; Ws[lk + 19][lr] = w1.w;
        __syncthreads();
        #pragma unroll
        for (int kk = 0; kk < 32; kk++) {
            float4 x0 = *(const float4*)&As[kk][tm];
            float4 y0 = *(const float4*)&Ws[kk][tn];
            float av[4] = {x0.x, x0.y, x0.z, x0.w};
            float bv[4] = {y0.x, y0.y, y0.z, y0.w};
            #pragma unroll
            for (int i = 0; i < 4; i++)
                #pragma unroll
                for (int j = 0; j < 4; j++) acc[i][j] = fmaf(av[i], bv[j], acc[i][j]);
        }
    }
    #pragma unroll
    for (int i = 0; i < 4; i++) {
        int m = m0 + tm + i;
        if (m >= M) continue;
        float* cr = C + (size_t)m * N;
        int n = n0 + tn;
        if (n < N) {
            float4 v = {acc[i][0], acc[i][1], acc[i][2], acc[i][3]};
            if (BIAS) { v.x += bias[n]; v.y += bias[n + 1]; v.z += bias[n + 2]; v.w += bias[n + 3]; }
            *(float4*)(cr + n) = v;
        }
    }
}

// ---------------- depthwise causal conv(4) + SiLU -> bf16 ----------------
__global__ void conv_silu_kernel(const float* __restrict__ xz, const float* __restrict__ cw,
                                 const float* __restrict__ cb, ushort_t* __restrict__ xcbf) {
    int idx = blockIdx.x * 256 + threadIdx.x;
    if (idx >= MROWS * DI) return;
    int e = idx % DI; int bl = idx / DI; int l = bl % SEQL; int b = bl / SEQL;
    const float* base = xz + (size_t)(b * SEQL) * 768 + e;
    float w0 = cw[e * 4], w1 = cw[e * 4 + 1], w2 = cw[e * 4 + 2], w3 = cw[e * 4 + 3];
    float acc = cb[e];
    if (l >= 3) acc = fmaf(base[(size_t)(l - 3) * 768], w0, acc);
    if (l >= 2) acc = fmaf(base[(size_t)(l - 2) * 768], w1, acc);
    if (l >= 1) acc = fmaf(base[(size_t)(l - 1) * 768], w2, acc);
    acc = fmaf(base[(size_t)l * 768], w3, acc);
    xcbf[idx] = f2bf(acc * sigmoidf_(acc));
}

// ---------------- wave-parallel chunked selective scan, v3 ----------------
// grid (64 b, 96 e-groups), block 256 = 4 waves; wave handles e = eg*4+wave.
// x_dbl comes in TRANSPOSED [b][44][196]: per-k rows are l-contiguous, so each
// lane (l-chunk of 4) reads float4 via conflict-free ds_read_b128.
// xc/z staged cooperatively; y staged in its own LDS buffer + ushort4 store.
// dA recomputed in pass 2 (exp is cheap; keeps live state ~65 floats).
__global__ __launch_bounds__(256) void scan_kernel(const float* __restrict__ xdt,
        const ushort_t* __restrict__ xcbf, const float* __restrict__ xz,
        const float* __restrict__ dtw, const float* __restrict__ dtb,
        const float* __restrict__ a_log, const float* __restrict__ Dp, ushort_t* __restrict__ y) {
    __shared__ float sd[44 * 196];       // 34496 B
    __shared__ float zs[4 * 200];        // [e_off][l] fp32
    __shared__ ushort_t xcs[4 * 200];    // [e_off][l] bf16
    __shared__ ushort_t ys[4 * 200];     // [e_off][l] bf16 (separate from xcs)
    const int b = blockIdx.x, eg = blockIdx.y;
    const int tid = threadIdx.x;
    const int wave = tid >> 6, lane = tid & 63;
    const int e = eg * 4 + wave;

    {   // stage x_dbl_t plane (contiguous float4 copy)
        const float4* src4 = (const float4*)(xdt + (size_t)b * XDP);
        float4* sd4 = (float4*)sd;
        for (int i = tid; i < XDP / 4; i += 256) sd4[i] = src4[i];
    }
    if (tid < 196) {  // stage xc (ushort4/l) and z (float4/l) for the 4 e's
        int l = tid;
        ushort4 xq = *(const ushort4*)(xcbf + (size_t)(b * SEQL + l) * DI + eg * 4);
        float4  zq = *(const float4*)(xz + (size_t)(b * SEQL + l) * 768 + DI + eg * 4);
        xcs[0 * 200 + l] = xq.x; xcs[1 * 200 + l] = xq.y;
        xcs[2 * 200 + l] = xq.z; xcs[3 * 200 + l] = xq.w;
        zs[0 * 200 + l] = zq.x; zs[1 * 200 + l] = zq.y;
        zs[2 * 200 + l] = zq.z; zs[3 * 200 + l] = zq.w;
    }
    __syncthreads();

    float wdt[DR];
    #pragma unroll
    for (int j = 0; j < DR; j++) wdt[j] = dtw[(size_t)e * DR + j];
    const float db = dtb[e], Dv = Dp[e];
    float Av[DS];
    #pragma unroll
    for (int n = 0; n < DS; n++) Av[n] = -__expf(a_log[(size_t)e * DS + n]);

    const bool act = lane < 49;
    const int lbase = act ? lane * 4 : 0;

    // delta = softplus(dt_row . wdt + db), 4 l's at once
    f32x4 dt4 = {db, db, db, db};
    #pragma unroll
    for (int k = 0; k < DR; k++) {
        f32x4 r = *(const f32x4*)&sd[k * 196 + lbase];
        dt4 += r * wdt[k];
    }
    f32x4 d4;
    #pragma unroll
    for (int s = 0; s < 4; s++) {
        float v = dt4[s];
        d4[s] = (v > 20.f) ? v : log1pf(__expf(v));
    }
    const ushort_t* xcw = &xcs[wave * 200 + lbase];
    f32x4 xcv4 = {bf2f(xcw[0]), bf2f(xcw[1]), bf2f(xcw[2]), bf2f(xcw[3])};
    f32x4 zv4 = *(const f32x4*)&zs[wave * 200 + lbase];
    f32x4 du4 = d4 * xcv4;

    // pass 1: local affine transform per lane-chunk
    float P[DS], h[DS];
    #pragma unroll
    for (int n = 0; n < DS; n++) { P[n] = 1.f; h[n] = 0.f; }
    if (act) {
        #pragma unroll
        for (int n = 0; n < DS; n++) {
            f32x4 Bn = *(const f32x4*)&sd[(12 + n) * 196 + lbase];
            float hn = 0.f, Pn = 1.f;
            #pragma unroll
            for (int s = 0; s < 4; s++) {
                float dA = __expf(d4[s] * Av[n]);
                hn = fmaf(hn, dA, du4[s] * Bn[s]);
                Pn *= dA;
            }
            P[n] = Pn; h[n] = hn;
        }
    }

    // Kogge-Stone inclusive scan of affine maps across lanes
    #pragma unroll
    for (int off = 1; off < 64; off <<= 1) {
        #pragma unroll
        for (int n = 0; n < DS; n++) {
            float Pp = __shfl_up(P[n], off);
            float Hp = __shfl_up(h[n], off);
            if (lane >= off) {
                h[n] = fmaf(P[n], Hp, h[n]);
                P[n] *= Pp;
            }
        }
    }
    #pragma unroll
    for (int n = 0; n < DS; n++) {  // exclusive: incoming state
        float Hp = __shfl_up(h[n], 1);
        h[n] = (lane == 0) ? 0.f : Hp;
    }

    // pass 2: replay with correct incoming state; y = h.C + xc*D, gate silu(z)
    if (act) {
        f32x4 acc4 = {0.f, 0.f, 0.f, 0.f};
        #pragma unroll
        for (int n = 0; n < DS; n++) {
            f32x4 Bn = *(const f32x4*)&sd[(12 + n) * 196 + lbase];
            f32x4 Cn = *(const f32x4*)&sd[(28 + n) * 196 + lbase];
            float hn = h[n];
            #pragma unroll
            for (int s = 0; s < 4; s++) {
                float dA = __expf(d4[s] * Av[n]);
                hn = fmaf(hn, dA, du4[s] * Bn[s]);
                acc4[s] = fmaf(hn, Cn[s], acc4[s]);
            }
        }
        ushort_t* yw = &ys[wave * 200 + lbase];
        #pragma unroll
        for (int s = 0; s < 4; s++) {
            float yv = fmaf(xcv4[s], Dv, acc4[s]);
            float zv = zv4[s];
            yw[s] = f2bf(yv * zv * sigmoidf_(zv));
        }
    }
    __syncthreads();
    if (tid < 196) {  // cooperative ushort4 store of y for the 4 e's
        int l = tid;
        ushort4 o;
        o.x = ys[0 * 200 + l]; o.y = ys[1 * 200 + l];
        o.z = ys[2 * 200 + l]; o.w = ys[3 * 200 + l];
        *(ushort4*)(y + (size_t)(b * SEQL + l) * DI + eg * 4) = o;
    }
}

// ---------------- mean over L ----------------
__global__ void pool_kernel(const float* __restrict__ normed, float* __restrict__ pooled) {
    int b = blockIdx.x, d = threadIdx.x;
    float s = 0.f;
    for (int l = 0; l < SEQL; l++) s += normed[(size_t)(b * SEQL + l) * DM + d];
    pooled[b * DM + d] = s * (1.f / 196.f);
}

extern "C" void kernel_launch(void* const* d_in, const int* in_sizes, int n_in,
                              void* d_out, int out_size, void* d_ws, size_t ws_size,
                              hipStream_t stream) {
    const float* x       = (const float*)d_in[0];
    const float* patch_w = (const float*)d_in[1];
    const float* patch_b = (const float*)d_in[2];
    const float* norm_w  = (const float*)d_in[3];
    const float* norm_b  = (const float*)d_in[4];
    const float* in_w    = (const float*)d_in[5];
    const float* conv_w  = (const float*)d_in[6];
    const float* conv_b  = (const float*)d_in[7];
    const float* xp_w    = (const float*)d_in[8];
    const float* dt_w    = (const float*)d_in[9];
    const float* dt_b    = (const float*)d_in[10];
    const float* A_log   = (const float*)d_in[11];
    const float* Dp      = (const float*)d_in[12];
    const float* out_w   = (const float*)d_in[13];
    const float* normf_w = (const float*)d_in[14];
    const float* normf_b = (const float*)d_in[15];
    const float* head_w  = (const float*)d_in[16];
    const float* head_b  = (const float*)d_in[17];

    float* ws = (float*)d_ws;
    // Disjoint layout (only alias: x_bf over xcbf+y_bf, round-4-validated).
    float* residual     = ws;                          // [0, 2408448)
    float* hidden       = ws + 2408448;                // [2408448, 4816896)
    float* xz           = ws + 4816896;                // [4816896, 14450688)
    ushort_t* xcbf      = (ushort_t*)(ws + 14450688);  // [14450688, 16859136)
    ushort_t* y_bf      = (ushort_t*)(ws + 16859136);  // [16859136, 19267584)
    ushort_t* x_bf      = (ushort_t*)(ws + 14450688);  // alias, dead before layer-0 conv
    ushort_t* normed_bf = (ushort_t*)(ws + 19267584);  // [19267584, 20471808)
    float* xdbl_t       = ws + 20471808;               // [20471808, 21023744)
    float* pooled       = ws + 21023744;               // [21023744, 21036032)
    ushort_t* in_w_bf   = (ushort_t*)(ws + 21036032);  // [21036032, 22805504)
    ushort_t* out_w_bf  = (ushort_t*)(ws + 22805504);  // [22805504, 23690240)
    ushort_t* xp_w_bf   = (ushort_t*)(ws + 23690240);  // [23690240, 23985152)
    ushort_t* patch_w_bf= (ushort_t*)(ws + 23985152);  // [23985152, 24058880)
    // end 24,058,880 floats = 96.2 MB (round 1 used 108.2 MB OK)

    hipMemsetAsync(residual, 0, (size_t)2408448 * sizeof(float), stream);

    f2bf4_kernel<<<3456, 256, 0, stream>>>(in_w, in_w_bf, 884736);
    f2bf4_kernel<<<1728, 256, 0, stream>>>(out_w, out_w_bf, 442368);
    f2bf4_kernel<<<144, 256, 0, stream>>>(patch_w, patch_w_bf, 36864);
    f2bf4_kernel<<<9408, 256, 0, stream>>>(x, x_bf, 2408448);
    xp_pad_kernel<<<2304, 256, 0, stream>>>(xp_w, xp_w_bf);

    gemm_patch_mfma<<<dim3(98, 3), 256, 0, stream>>>(x_bf, patch_w_bf, patch_b, hidden);

    for (int d = 0; d < DEPTH; ++d) {
        ln_kernel<true><<<3136, 256, 0, stream>>>(residual, hidden, norm_w + d * DM,
                                                  norm_b + d * DM, normed_bf);
        gemm_mfma<192, 2, 2, 12, false><<<dim3(98, 4), 256, 0, stream>>>(normed_bf,
                in_w_bf + (size_t)d * 768 * 192, xz, 192, 768);
        conv_silu_kernel<<<18816, 256, 0, stream>>>(xz, conv_w + d * DI * 4, conv_b + d * DI, xcbf);
        // x_proj -> transposed x_dbl [b][44][196]
        gemm_mfma<64, 4, 1, 3, true><<<dim3(98, 1), 256, 0, stream>>>(xcbf,
                xp_w_bf + (size_t)d * 64 * 384, xdbl_t, 384, 196);
        scan_kernel<<<dim3(64, 96), 256, 0, stream>>>(xdbl_t, xcbf, xz, dt_w + d * DI * DR,
                dt_b + d * DI, A_log + d * DI * DS, Dp + d * DI, y_bf);
        gemm_mfma<64, 4, 1, 4, false><<<dim3(98, 3), 256, 0, stream>>>(y_bf,
                out_w_bf + (size_t)d * 192 * 384, hidden, 384, 192);
    }

    ln_kernel<false><<<3136, 256, 0, stream>>>(residual, hidden, normf_w, normf_b, xz);
    pool_kernel<<<64, 192, 0, stream>>>(xz, pooled);
    gemm64<true><<<dim3(1, 16), 256, 0, stream>>>(pooled, head_w, head_b, (float*)d_out, 64, 1000, 192);
}

// Round 8
// 4113.046 us; speedup vs baseline: 1.0615x; 1.0615x over previous
//
#include <hip/hip_runtime.h>
#include <math.h>

// VisionMamba forward. Round 8: scan v4 — 512-thread blocks (8 waves, 8 e)
// share one 34.5 KB x_dbl plane; z staged bf16. Occupancy 21% -> ~50%.
// Everything else identical to round 7 (which passed, absmax 9.8e-4).
// B=64, L=196, D_MODEL=192, D_INNER=384, D_STATE=16, DT_RANK=12, DEPTH=24.

#define DEPTH 24
#define DM 192
#define DI 384
#define DS 16
#define DR 12
#define SEQL 196
#define BATCH 64
#define MROWS (BATCH*SEQL)   // 12544
#define XDP 8624             // x_dbl_t per-b plane: 44*196 floats

typedef unsigned short ushort_t;
typedef __bf16 bf16x8 __attribute__((ext_vector_type(8)));
typedef float f32x4 __attribute__((ext_vector_type(4)));

__device__ __forceinline__ float sigmoidf_(float x) { return 1.f / (1.f + __expf(-x)); }

__device__ __forceinline__ ushort_t f2bf(float f) {  // RNE fp32->bf16
    union { float f; unsigned u; } c; c.f = f;
    unsigned u = c.u;
    return (ushort_t)((u + 0x7FFFu + ((u >> 16) & 1u)) >> 16);
}
__device__ __forceinline__ float bf2f(ushort_t u) {
    union { unsigned u; float f; } c; c.u = ((unsigned)u) << 16;
    return c.f;
}

__device__ __forceinline__ void load_lds16(const ushort_t* g, ushort_t* l) {
    __builtin_amdgcn_global_load_lds((__attribute__((address_space(1))) void*)g,
                                     (__attribute__((address_space(3))) void*)l, 16, 0, 0);
}

// ---------------- fp32 -> bf16 bulk convert, 4 elems/thread ----------------
__global__ void f2bf4_kernel(const float* __restrict__ src, ushort_t* __restrict__ dst, int n4) {
    int i = blockIdx.x * 256 + threadIdx.x;
    if (i >= n4) return;
    float4 v = ((const float4*)src)[i];
    union { ushort_t s[4]; uint2 u; } o;
    o.s[0] = f2bf(v.x); o.s[1] = f2bf(v.y); o.s[2] = f2bf(v.z); o.s[3] = f2bf(v.w);
    ((uint2*)dst)[i] = o.u;
}

// xp_w [24][44][384] -> padded bf16 [24][64][384], rows 44..63 = 0
__global__ void xp_pad_kernel(const float* __restrict__ src, ushort_t* __restrict__ dst) {
    int i = blockIdx.x * 256 + threadIdx.x;
    if (i >= DEPTH * 64 * 384) return;
    int col = i % 384, row = (i / 384) & 63, d = i / (384 * 64);
    float v = (row < 44) ? src[(size_t)d * 44 * 384 + row * 384 + col] : 0.f;
    dst[i] = f2bf(v);
}

// ---------------- residual += hidden; out = LayerNorm(residual) ----------------
template<bool BF>
__global__ void ln_kernel(float* __restrict__ residual, const float* __restrict__ hidden,
                          const float* __restrict__ w, const float* __restrict__ b,
                          void* __restrict__ out_) {
    int wave = threadIdx.x >> 6, lane = threadIdx.x & 63;
    int row = blockIdx.x * 4 + wave;
    float* rr = residual + (size_t)row * DM;
    const float* hr = hidden + (size_t)row * DM;
    float v0 = rr[lane]       + hr[lane];
    float v1 = rr[lane + 64]  + hr[lane + 64];
    float v2 = rr[lane + 128] + hr[lane + 128];
    rr[lane] = v0; rr[lane + 64] = v1; rr[lane + 128] = v2;
    float s = v0 + v1 + v2;
    #pragma unroll
    for (int off = 32; off > 0; off >>= 1) s += __shfl_down(s, off);
    float mean = __shfl(s, 0) * (1.f / DM);
    float d0 = v0 - mean, d1 = v1 - mean, d2 = v2 - mean;
    float q = d0 * d0 + d1 * d1 + d2 * d2;
    #pragma unroll
    for (int off = 32; off > 0; off >>= 1) q += __shfl_down(q, off);
    float rstd = rsqrtf(__shfl(q, 0) * (1.f / DM) + 1e-5f);
    float o0 = d0 * rstd * w[lane]       + b[lane];
    float o1 = d1 * rstd * w[lane + 64]  + b[lane + 64];
    float o2 = d2 * rstd * w[lane + 128] + b[lane + 128];
    if constexpr (BF) {
        ushort_t* o = (ushort_t*)out_ + (size_t)row * DM;
        o[lane] = f2bf(o0); o[lane + 64] = f2bf(o1); o[lane + 128] = f2bf(o2);
    } else {
        float* o = (float*)out_ + (size_t)row * DM;
        o[lane] = o0; o[lane + 64] = o1; o[lane + 128] = o2;
    }
}

// ---------------- bf16 MFMA GEMM: C = A[M,K]bf16 * W[N,K]bf16^T ----------------
template<int BN, int WM, int WN, int NST, bool TC>
__global__ __launch_bounds__(256, 2) void gemm_mfma(const ushort_t* __restrict__ A,
        const ushort_t* __restrict__ W, float* __restrict__ C, int K, int ldC) {
    constexpr int FM = 128 / (WM * 16);
    constexpr int FN = BN / (WN * 16);
    __shared__ ushort_t sA[128 * 32];
    __shared__ ushort_t sB[BN * 32];
    const int t = threadIdx.x;
    const int wave = t >> 6, lane = t & 63;
    const int lr = lane & 15, lq = lane >> 4;
    const int wr = wave / WN, wc = wave % WN;
    const int m0 = blockIdx.x * 128, n0 = blockIdx.y * BN;
    const int wbase = t & ~63;

    f32x4 acc[FM][FN];
    #pragma unroll
    for (int i = 0; i < FM; i++)
        #pragma unroll
        for (int j = 0; j < FN; j++) acc[i][j] = f32x4{0.f, 0.f, 0.f, 0.f};

    for (int k0 = 0; k0 < K; k0 += 32) {
        __syncthreads();
        #pragma unroll
        for (int c = 0; c < 2; c++) {           // A: 512 slots
            int s = c * 256 + t;
            int row = s >> 2;
            int quad = (s & 3) ^ ((row >> 1) & 3);
            load_lds16(A + (size_t)(m0 + row) * K + k0 + quad * 8,
                       sA + (size_t)(c * 256 + wbase) * 8);
        }
        #pragma unroll
        for (int c = 0; c < BN * 4 / 256; c++) { // B: BN*4 slots
            int s = c * 256 + t;
            int row = s >> 2;
            int quad = (s & 3) ^ ((row >> 1) & 3);
            load_lds16(W + (size_t)(n0 + row) * K + k0 + quad * 8,
                       sB + (size_t)(c * 256 + wbase) * 8);
        }
        __syncthreads();
        bf16x8 af[FM], bfr[FN];
        #pragma unroll
        for (int i = 0; i < FM; i++) {
            int row = wr * FM * 16 + i * 16 + lr;
            int slot = (row << 2) | (lq ^ ((row >> 1) & 3));
            af[i] = *(const bf16x8*)&sA[(size_t)slot * 8];
        }
        #pragma unroll
        for (int j = 0; j < FN; j++) {
            int row = wc * FN * 16 + j * 16 + lr;
            int slot = (row << 2) | (lq ^ ((row >> 1) & 3));
            bfr[j] = *(const bf16x8*)&sB[(size_t)slot * 8];
        }
        #pragma unroll
        for (int i = 0; i < FM; i++)
            #pragma unroll
            for (int j = 0; j < FN; j++)
                acc[i][j] = __builtin_amdgcn_mfma_f32_16x16x32_bf16(af[i], bfr[j], acc[i][j], 0, 0, 0);
    }
    // C/D layout: col = lane&15, row = (lane>>4)*4 + reg
    int crow0 = m0 + wr * FM * 16 + lq * 4;
    int ccol0 = n0 + wc * FN * 16 + lr;
    if constexpr (TC) {
        #pragma unroll
        for (int i = 0; i < FM; i++) {
            int m = crow0 + i * 16;
            int bb = m / 196, l = m % 196;
            #pragma unroll
            for (int j = 0; j < FN; j++) {
                int col = ccol0 + j * 16;
                if (col < 44) {
                    float4 v = {acc[i][j][0], acc[i][j][1], acc[i][j][2], acc[i][j][3]};
                    *(float4*)(C + (size_t)bb * XDP + (size_t)col * 196 + l) = v;
                }
            }
        }
    } else {
        #pragma unroll
        for (int i = 0; i < FM; i++)
            #pragma unroll
            for (int j = 0; j < FN; j++) {
                if (wc * FN + j >= NST) continue;
                float* cp = C + (size_t)(crow0 + i * 16) * ldC + ccol0 + j * 16;
                #pragma unroll
                for (int r = 0; r < 4; r++) cp[(size_t)r * ldC] = acc[i][j][r];
            }
    }
}

// ---------------- Patch-embed bf16 MFMA with im2col A-loader ----------------
__global__ __launch_bounds__(256, 2) void gemm_patch_mfma(const ushort_t* __restrict__ Xbf,
        const ushort_t* __restrict__ Wbf, const float* __restrict__ bias, float* __restrict__ C) {
    constexpr int FM = 2, FN = 4;
    __shared__ ushort_t sA[128 * 32];
    __shared__ ushort_t sB[64 * 32];
    const int t = threadIdx.x;
    const int wave = t >> 6, lane = t & 63;
    const int lr = lane & 15, lq = lane >> 4;
    const int m0 = blockIdx.x * 128, n0 = blockIdx.y * 64;
    const int wbase = t & ~63;

    const ushort_t* abase[2];
    int aquad[2];
    #pragma unroll
    for (int c = 0; c < 2; c++) {
        int s = c * 256 + t;
        int row = s >> 2;
        aquad[c] = (s & 3) ^ ((row >> 1) & 3);
        int m = m0 + row;
        int b = m / 196, r = m % 196, py = r / 14, px = r % 14;
        abase[c] = Xbf + (size_t)b * 150528 + py * 3584 + px * 16;
    }
    int brow = t >> 2;
    int bquad = (t & 3) ^ ((brow >> 1) & 3);
    const ushort_t* bbase = Wbf + (size_t)(n0 + brow) * 768 + bquad * 8;

    f32x4 acc[FM][FN];
    #pragma unroll
    for (int i = 0; i < FM; i++)
        #pragma unroll
        for (int j = 0; j < FN; j++) acc[i][j] = f32x4{0.f, 0.f, 0.f, 0.f};

    for (int k0 = 0; k0 < 768; k0 += 32) {
        __syncthreads();
        #pragma unroll
        for (int c = 0; c < 2; c++) {
            int k = k0 + aquad[c] * 8;
            int ci = k >> 8, ky = (k >> 4) & 15, kx0 = k & 15;
            load_lds16(abase[c] + ci * 50176 + ky * 224 + kx0,
                       sA + (size_t)(c * 256 + wbase) * 8);
        }
        load_lds16(bbase + k0, sB + (size_t)wbase * 8);
        __syncthreads();
        bf16x8 af[FM], bfr[FN];
        #pragma unroll
        for (int i = 0; i < FM; i++) {
            int row = wave * FM * 16 + i * 16 + lr;
            int slot = (row << 2) | (lq ^ ((row >> 1) & 3));
            af[i] = *(const bf16x8*)&sA[(size_t)slot * 8];
        }
        #pragma unroll
        for (int j = 0; j < FN; j++) {
            int row = j * 16 + lr;
            int slot = (row << 2) | (lq ^ ((row >> 1) & 3));
            bfr[j] = *(const bf16x8*)&sB[(size_t)slot * 8];
        }
        #pragma unroll
        for (int i = 0; i < FM; i++)
            #pragma unroll
            for (int j = 0; j < FN; j++)
                acc[i][j] = __builtin_amdgcn_mfma_f32_16x16x32_bf16(af[i], bfr[j], acc[i][j], 0, 0, 0);
    }
    int crow0 = m0 + wave * FM * 16 + lq * 4;
    int ccol0 = n0 + lr;
    #pragma unroll
    for (int i = 0; i < FM; i++)
        #pragma unroll
        for (int j = 0; j < FN; j++) {
            int col = ccol0 + j * 16;
            float bv = bias[col];
            float* cp = C + (size_t)(crow0 + i * 16) * DM + col;
            #pragma unroll
            for (int r = 0; r < 4; r++) cp[(size_t)r * DM] = acc[i][j][r] + bv;
        }
}

// ---------------- Small fp32 GEMM (head only) ----------------
template<bool BIAS>
__global__ __launch_bounds__(256, 2) void gemm64(const float* __restrict__ A,
        const float* __restrict__ W, const float* __restrict__ bias,
        float* __restrict__ C, int M, int N, int K) {
    __shared__ float As[32][68];
    __shared__ float Ws[32][68];
    int t = threadIdx.x;
    int m0 = blockIdx.x * 64, n0 = blockIdx.y * 64;
    int lr = t >> 2, lk = (t & 3) * 4;
    int am = m0 + lr; bool avld = am < M;
    const float* Ap = A + (size_t)(avld ? am : 0) * K + lk;
    int wn = n0 + lr; bool wv = wn < N;
    const float* Wp = W + (size_t)(wv ? wn : 0) * K + lk;
    int tm = (t >> 4) * 4, tn = (t & 15) * 4;
    float acc[4][4];
    #pragma unroll
    for (int i = 0; i < 4; i++)
        #pragma unroll
        for (int j = 0; j < 4; j++) acc[i][j] = 0.f;

    for (int k0 = 0; k0 < K; k0 += 32) {
        float4 a0 = make_float4(0.f, 0.f, 0.f, 0.f), a1 = a0, w0 = a0, w1 = a0;
        if (avld) { a0 = *(const float4*)(Ap + k0); a1 = *(const float4*)(Ap + k0 + 16); }
        if (wv)   { w0 = *(const float4*)(Wp + k0); w1 = *(const float4*)(Wp + k0 + 16); }
        __syncthreads();
        As[lk + 0][lr] = a0.x; As[lk + 1][lr] = a0.y; As[lk + 2][lr] = a0.z; As[lk + 3][lr] = a0.w;
        As[lk + 16][lr] = a1.x; As[lk + 17][lr] = a1.y; As[lk + 18][lr] = a1.z; As[lk + 19][lr] = a1.w;
        Ws[lk + 0][lr] = w0.x; Ws[lk + 1][lr] = w0.y; Ws[lk + 2][lr] = w0.z; Ws[lk + 3][lr] = w0.w;
        Ws[lk + 16][lr] = w1.x; Ws[lk + 17][lr] = w1.y; Ws[lk + 18][lr] = w1.z; Ws[lk + 19][lr] = w1.w;
        __syncthreads();
        #pragma unroll
        for (int kk = 0; kk < 32; kk++) {
            float4 x0 = *(const float4*)&As[kk][tm];
            float4 y0 = *(const float4*)&Ws[kk][tn];
            float av[4] = {x0.x, x0.y, x0.z, x0.w};
            float bv[4] = {y0.x, y0.y, y0.z, y0.w};
            #pragma unroll
            for (int i = 0; i < 4; i++)
                #pragma unroll
                for (int j = 0; j < 4; j++) acc[i][j] = fmaf(av[i], bv[j], acc[i][j]);
        }
    }
    #pragma unroll
    for (int i = 0; i < 4; i++) {
        int m = m0 + tm + i;
        if (m >= M) continue;
        float* cr = C + (size_t)m * N;
        int n = n0 + tn;
        if (n < N) {
            float4 v = {acc[i][0], acc[i][1], acc[i][2], acc[i][3]};
            if (BIAS) { v.x += bias[n]; v.y += bias[n + 1]; v.z += bias[n + 2]; v.w += bias[n + 3]; }
            *(float4*)(cr + n) = v;
        }
    }
}

// ---------------- depthwise causal conv(4) + SiLU -> bf16 ----------------
__global__ void conv_silu_kernel(const float* __restrict__ xz, const float* __restrict__ cw,
                                 const float* __restrict__ cb, ushort_t* __restrict__ xcbf) {
    int idx = blockIdx.x * 256 + threadIdx.x;
    if (idx >= MROWS * DI) return;
    int e = idx % DI; int bl = idx / DI; int l = bl % SEQL; int b = bl / SEQL;
    const float* base = xz + (size_t)(b * SEQL) * 768 + e;
    float w0 = cw[e * 4], w1 = cw[e * 4 + 1], w2 = cw[e * 4 + 2], w3 = cw[e * 4 + 3];
    float acc = cb[e];
    if (l >= 3) acc = fmaf(base[(size_t)(l - 3) * 768], w0, acc);
    if (l >= 2) acc = fmaf(base[(size_t)(l - 2) * 768], w1, acc);
    if (l >= 1) acc = fmaf(base[(size_t)(l - 1) * 768], w2, acc);
    acc = fmaf(base[(size_t)l * 768], w3, acc);
    xcbf[idx] = f2bf(acc * sigmoidf_(acc));
}

// ---------------- wave-parallel chunked selective scan, v4 ----------------
// grid (64 b, 48 e-groups), block 512 = 8 waves; wave handles e = eg*8+wave.
// One 34.5 KB x_dbl plane serves 8 waves (vs 4) -> 2 blocks/CU, 16 waves/CU.
// z staged as bf16. Per-wave math identical to round 7.
__global__ __launch_bounds__(512, 5) void scan_kernel(const float* __restrict__ xdt,
        const ushort_t* __restrict__ xcbf, const float* __restrict__ xz,
        const float* __restrict__ dtw, const float* __restrict__ dtb,
        const float* __restrict__ a_log, const float* __restrict__ Dp, ushort_t* __restrict__ y) {
    __shared__ float sd[44 * 196];       // 34496 B
    __shared__ ushort_t zs[8 * 200];     // [e_off][l] bf16, 3200 B
    __shared__ ushort_t xcs[8 * 200];    // [e_off][l] bf16, 3200 B
    __shared__ ushort_t ys[8 * 200];     // [e_off][l] bf16, 3200 B
    const int b = blockIdx.x, eg = blockIdx.y;
    const int tid = threadIdx.x;
    const int wave = tid >> 6, lane = tid & 63;
    const int e = eg * 8 + wave;

    {   // stage x_dbl_t plane (contiguous float4 copy)
        const float4* src4 = (const float4*)(xdt + (size_t)b * XDP);
        float4* sd4 = (float4*)sd;
        for (int i = tid; i < XDP / 4; i += 512) sd4[i] = src4[i];
    }
    if (tid < 196) {  // stage xc and z (bf16) for the 8 e's
        int l = tid;
        const ushort_t* xp = xcbf + (size_t)(b * SEQL + l) * DI + eg * 8;
        ushort4 xq0 = *(const ushort4*)xp;
        ushort4 xq1 = *(const ushort4*)(xp + 4);
        const float* zp = xz + (size_t)(b * SEQL + l) * 768 + DI + eg * 8;
        float4 zq0 = *(const float4*)zp;
        float4 zq1 = *(const float4*)(zp + 4);
        xcs[0 * 200 + l] = xq0.x; xcs[1 * 200 + l] = xq0.y;
        xcs[2 * 200 + l] = xq0.z; xcs[3 * 200 + l] = xq0.w;
        xcs[4 * 200 + l] = xq1.x; xcs[5 * 200 + l] = xq1.y;
        xcs[6 * 200 + l] = xq1.z; xcs[7 * 200 + l] = xq1.w;
        zs[0 * 200 + l] = f2bf(zq0.x); zs[1 * 200 + l] = f2bf(zq0.y);
        zs[2 * 200 + l] = f2bf(zq0.z); zs[3 * 200 + l] = f2bf(zq0.w);
        zs[4 * 200 + l] = f2bf(zq1.x); zs[5 * 200 + l] = f2bf(zq1.y);
        zs[6 * 200 + l] = f2bf(zq1.z); zs[7 * 200 + l] = f2bf(zq1.w);
    }
    __syncthreads();

    float wdt[DR];
    #pragma unroll
    for (int j = 0; j < DR; j++) wdt[j] = dtw[(size_t)e * DR + j];
    const float db = dtb[e], Dv = Dp[e];
    float Av[DS];
    #pragma unroll
    for (int n = 0; n < DS; n++) Av[n] = -__expf(a_log[(size_t)e * DS + n]);

    const bool act = lane < 49;
    const int lbase = act ? lane * 4 : 0;

    // delta = softplus(dt_row . wdt + db), 4 l's at once
    f32x4 dt4 = {db, db, db, db};
    #pragma unroll
    for (int k = 0; k < DR; k++) {
        f32x4 r = *(const f32x4*)&sd[k * 196 + lbase];
        dt4 += r * wdt[k];
    }
    f32x4 d4;
    #pragma unroll
    for (int s = 0; s < 4; s++) {
        float v = dt4[s];
        d4[s] = (v > 20.f) ? v : log1pf(__expf(v));
    }
    ushort4 xcq = *(const ushort4*)&xcs[wave * 200 + lbase];
    f32x4 xcv4 = {bf2f(xcq.x), bf2f(xcq.y), bf2f(xcq.z), bf2f(xcq.w)};
    ushort4 zq = *(const ushort4*)&zs[wave * 200 + lbase];
    f32x4 zv4 = {bf2f(zq.x), bf2f(zq.y), bf2f(zq.z), bf2f(zq.w)};
    f32x4 du4 = d4 * xcv4;

    // pass 1: local affine transform per lane-chunk
    float P[DS], h[DS];
    #pragma unroll
    for (int n = 0; n < DS; n++) { P[n] = 1.f; h[n] = 0.f; }
    if (act) {
        #pragma unroll
        for (int n = 0; n < DS; n++) {
            f32x4 Bn = *(const f32x4*)&sd[(12 + n) * 196 + lbase];
            float hn = 0.f, Pn = 1.f;
            #pragma unroll
            for (int s = 0; s < 4; s++) {
                float dA = __expf(d4[s] * Av[n]);
                hn = fmaf(hn, dA, du4[s] * Bn[s]);
                Pn *= dA;
            }
            P[n] = Pn; h[n] = hn;
        }
    }

    // Kogge-Stone inclusive scan of affine maps across lanes
    #pragma unroll
    for (int off = 1; off < 64; off <<= 1) {
        #pragma unroll
        for (int n = 0; n < DS; n++) {
            float Pp = __shfl_up(P[n], off);
            float Hp = __shfl_up(h[n], off);
            if (lane >= off) {
                h[n] = fmaf(P[n], Hp, h[n]);
                P[n] *= Pp;
            }
        }
    }
    #pragma unroll
    for (int n = 0; n < DS; n++) {  // exclusive: incoming state
        float Hp = __shfl_up(h[n], 1);
        h[n] = (lane == 0) ? 0.f : Hp;
    }

    // pass 2: replay with correct incoming state; y = h.C + xc*D, gate silu(z)
    if (act) {
        f32x4 acc4 = {0.f, 0.f, 0.f, 0.f};
        #pragma unroll
        for (int n = 0; n < DS; n++) {
            f32x4 Bn = *(const f32x4*)&sd[(12 + n) * 196 + lbase];
            f32x4 Cn = *(const f32x4*)&sd[(28 + n) * 196 + lbase];
            float hn = h[n];
            #pragma unroll
            for (int s = 0; s < 4; s++) {
                float dA = __expf(d4[s] * Av[n]);
                hn = fmaf(hn, dA, du4[s] * Bn[s]);
                acc4[s] = fmaf(hn, Cn[s], acc4[s]);
            }
        }
        ushort_t* yw = &ys[wave * 200 + lbase];
        #pragma unroll
        for (int s = 0; s < 4; s++) {
            float yv = fmaf(xcv4[s], Dv, acc4[s]);
            float zv = zv4[s];
            yw[s] = f2bf(yv * zv * sigmoidf_(zv));
        }
    }
    __syncthreads();
    if (tid < 196) {  // cooperative store of y for the 8 e's
        int l = tid;
        ushort4 o0, o1;
        o0.x = ys[0 * 200 + l]; o0.y = ys[1 * 200 + l];
        o0.z = ys[2 * 200 + l]; o0.w = ys[3 * 200 + l];
        o1.x = ys[4 * 200 + l]; o1.y = ys[5 * 200 + l];
        o1.z = ys[6 * 200 + l]; o1.w = ys[7 * 200 + l];
        ushort_t* yp = y + (size_t)(b * SEQL + l) * DI + eg * 8;
        *(ushort4*)yp = o0;
        *(ushort4*)(yp + 4) = o1;
    }
}

// ---------------- mean over L ----------------
__global__ void pool_kernel(const float* __restrict__ normed, float* __restrict__ pooled) {
    int b = blockIdx.x, d = threadIdx.x;
    float s = 0.f;
    for (int l = 0; l < SEQL; l++) s += normed[(size_t)(b * SEQL + l) * DM + d];
    pooled[b * DM + d] = s * (1.f / 196.f);
}

extern "C" void kernel_launch(void* const* d_in, const int* in_sizes, int n_in,
                              void* d_out, int out_size, void* d_ws, size_t ws_size,
                              hipStream_t stream) {
    const float* x       = (const float*)d_in[0];
    const float* patch_w = (const float*)d_in[1];
    const float* patch_b = (const float*)d_in[2];
    const float* norm_w  = (const float*)d_in[3];
    const float* norm_b  = (const float*)d_in[4];
    const float* in_w    = (const float*)d_in[5];
    const float* conv_w  = (const float*)d_in[6];
    const float* conv_b  = (const float*)d_in[7];
    const float* xp_w    = (const float*)d_in[8];
    const float* dt_w    = (const float*)d_in[9];
    const float* dt_b    = (const float*)d_in[10];
    const float* A_log   = (const float*)d_in[11];
    const float* Dp      = (const float*)d_in[12];
    const float* out_w   = (const float*)d_in[13];
    const float* normf_w = (const float*)d_in[14];
    const float* normf_b = (const float*)d_in[15];
    const float* head_w  = (const float*)d_in[16];
    const float* head_b  = (const float*)d_in[17];

    float* ws = (float*)d_ws;
    // Disjoint layout (only alias: x_bf over xcbf+y_bf, round-4-validated).
    float* residual     = ws;                          // [0, 2408448)
    float* hidden       = ws + 2408448;                // [2408448, 4816896)
    float* xz           = ws + 4816896;                // [4816896, 14450688)
    ushort_t* xcbf      = (ushort_t*)(ws + 14450688);  // [14450688, 16859136)
    ushort_t* y_bf      = (ushort_t*)(ws + 16859136);  // [16859136, 19267584)
    ushort_t* x_bf      = (ushort_t*)(ws + 14450688);  // alias, dead before layer-0 conv
    ushort_t* normed_bf = (ushort_t*)(ws + 19267584);  // [19267584, 20471808)
    float* xdbl_t       = ws + 20471808;               // [20471808, 21023744)
    float* pooled       = ws + 21023744;               // [21023744, 21036032)
    ushort_t* in_w_bf   = (ushort_t*)(ws + 21036032);  // [21036032, 22805504)
    ushort_t* out_w_bf  = (ushort_t*)(ws + 22805504);  // [22805504, 23690240)
    ushort_t* xp_w_bf   = (ushort_t*)(ws + 23690240);  // [23690240, 23985152)
    ushort_t* patch_w_bf= (ushort_t*)(ws + 23985152);  // [23985152, 24058880)
    // end 24,058,880 floats = 96.2 MB

    hipMemsetAsync(residual, 0, (size_t)2408448 * sizeof(float), stream);

    f2bf4_kernel<<<3456, 256, 0, stream>>>(in_w, in_w_bf, 884736);
    f2bf4_kernel<<<1728, 256, 0, stream>>>(out_w, out_w_bf, 442368);
    f2bf4_kernel<<<144, 256, 0, stream>>>(patch_w, patch_w_bf, 36864);
    f2bf4_kernel<<<9408, 256, 0, stream>>>(x, x_bf, 2408448);
    xp_pad_kernel<<<2304, 256, 0, stream>>>(xp_w, xp_w_bf);

    gemm_patch_mfma<<<dim3(98, 3), 256, 0, stream>>>(x_bf, patch_w_bf, patch_b, hidden);

    for (int d = 0; d < DEPTH; ++d) {
        ln_kernel<true><<<3136, 256, 0, stream>>>(residual, hidden, norm_w + d * DM,
                                                  norm_b + d * DM, normed_bf);
        gemm_mfma<192, 2, 2, 12, false><<<dim3(98, 4), 256, 0, stream>>>(normed_bf,
                in_w_bf + (size_t)d * 768 * 192, xz, 192, 768);
        conv_silu_kernel<<<18816, 256, 0, stream>>>(xz, conv_w + d * DI * 4, conv_b + d * DI, xcbf);
        // x_proj -> transposed x_dbl [b][44][196]
        gemm_mfma<64, 4, 1, 3, true><<<dim3(98, 1), 256, 0, stream>>>(xcbf,
                xp_w_bf + (size_t)d * 64 * 384, xdbl_t, 384, 196);
        scan_kernel<<<dim3(64, 48), 512, 0, stream>>>(xdbl_t, xcbf, xz, dt_w + d * DI * DR,
                dt_b + d * DI, A_log + d * DI * DS, Dp + d * DI, y_bf);
        gemm_mfma<64, 4, 1, 4, false><<<dim3(98, 3), 256, 0, stream>>>(y_bf,
                out_w_bf + (size_t)d * 192 * 384, hidden, 384, 192);
    }

    ln_kernel<false><<<3136, 256, 0, stream>>>(residual, hidden, normf_w, normf_b, xz);
    pool_kernel<<<64, 192, 0, stream>>>(xz, pooled);
    gemm64<true><<<dim3(1, 16), 256, 0, stream>>>(pooled, head_w, head_b, (float*)d_out, 64, 1000, 192);
}

// Round 9
// 3760.184 us; speedup vs baseline: 1.1611x; 1.0938x over previous
//
#include <hip/hip_runtime.h>
#include <math.h>

// VisionMamba forward. Round 9: scan v5 — fix round-8 scratch spill.
// 512-thread scan keeps the shared 34.5 KB x_dbl plane, but: launch_bounds
// (512,4) (VGPR cap 128, no forced spill) and wave-uniform Av/wdt moved to
// per-wave LDS (broadcast reads) to drop ~28 VGPRs of live state.
// B=64, L=196, D_MODEL=192, D_INNER=384, D_STATE=16, DT_RANK=12, DEPTH=24.

#define DEPTH 24
#define DM 192
#define DI 384
#define DS 16
#define DR 12
#define SEQL 196
#define BATCH 64
#define MROWS (BATCH*SEQL)   // 12544
#define XDP 8624             // x_dbl_t per-b plane: 44*196 floats

typedef unsigned short ushort_t;
typedef __bf16 bf16x8 __attribute__((ext_vector_type(8)));
typedef float f32x4 __attribute__((ext_vector_type(4)));

__device__ __forceinline__ float sigmoidf_(float x) { return 1.f / (1.f + __expf(-x)); }

__device__ __forceinline__ ushort_t f2bf(float f) {  // RNE fp32->bf16
    union { float f; unsigned u; } c; c.f = f;
    unsigned u = c.u;
    return (ushort_t)((u + 0x7FFFu + ((u >> 16) & 1u)) >> 16);
}
__device__ __forceinline__ float bf2f(ushort_t u) {
    union { unsigned u; float f; } c; c.u = ((unsigned)u) << 16;
    return c.f;
}

__device__ __forceinline__ void load_lds16(const ushort_t* g, ushort_t* l) {
    __builtin_amdgcn_global_load_lds((__attribute__((address_space(1))) void*)g,
                                     (__attribute__((address_space(3))) void*)l, 16, 0, 0);
}

// ---------------- fp32 -> bf16 bulk convert, 4 elems/thread ----------------
__global__ void f2bf4_kernel(const float* __restrict__ src, ushort_t* __restrict__ dst, int n4) {
    int i = blockIdx.x * 256 + threadIdx.x;
    if (i >= n4) return;
    float4 v = ((const float4*)src)[i];
    union { ushort_t s[4]; uint2 u; } o;
    o.s[0] = f2bf(v.x); o.s[1] = f2bf(v.y); o.s[2] = f2bf(v.z); o.s[3] = f2bf(v.w);
    ((uint2*)dst)[i] = o.u;
}

// xp_w [24][44][384] -> padded bf16 [24][64][384], rows 44..63 = 0
__global__ void xp_pad_kernel(const float* __restrict__ src, ushort_t* __restrict__ dst) {
    int i = blockIdx.x * 256 + threadIdx.x;
    if (i >= DEPTH * 64 * 384) return;
    int col = i % 384, row = (i / 384) & 63, d = i / (384 * 64);
    float v = (row < 44) ? src[(size_t)d * 44 * 384 + row * 384 + col] : 0.f;
    dst[i] = f2bf(v);
}

// ---------------- residual += hidden; out = LayerNorm(residual) ----------------
template<bool BF>
__global__ void ln_kernel(float* __restrict__ residual, const float* __restrict__ hidden,
                          const float* __restrict__ w, const float* __restrict__ b,
                          void* __restrict__ out_) {
    int wave = threadIdx.x >> 6, lane = threadIdx.x & 63;
    int row = blockIdx.x * 4 + wave;
    float* rr = residual + (size_t)row * DM;
    const float* hr = hidden + (size_t)row * DM;
    float v0 = rr[lane]       + hr[lane];
    float v1 = rr[lane + 64]  + hr[lane + 64];
    float v2 = rr[lane + 128] + hr[lane + 128];
    rr[lane] = v0; rr[lane + 64] = v1; rr[lane + 128] = v2;
    float s = v0 + v1 + v2;
    #pragma unroll
    for (int off = 32; off > 0; off >>= 1) s += __shfl_down(s, off);
    float mean = __shfl(s, 0) * (1.f / DM);
    float d0 = v0 - mean, d1 = v1 - mean, d2 = v2 - mean;
    float q = d0 * d0 + d1 * d1 + d2 * d2;
    #pragma unroll
    for (int off = 32; off > 0; off >>= 1) q += __shfl_down(q, off);
    float rstd = rsqrtf(__shfl(q, 0) * (1.f / DM) + 1e-5f);
    float o0 = d0 * rstd * w[lane]       + b[lane];
    float o1 = d1 * rstd * w[lane + 64]  + b[lane + 64];
    float o2 = d2 * rstd * w[lane + 128] + b[lane + 128];
    if constexpr (BF) {
        ushort_t* o = (ushort_t*)out_ + (size_t)row * DM;
        o[lane] = f2bf(o0); o[lane + 64] = f2bf(o1); o[lane + 128] = f2bf(o2);
    } else {
        float* o = (float*)out_ + (size_t)row * DM;
        o[lane] = o0; o[lane + 64] = o1; o[lane + 128] = o2;
    }
}

// ---------------- bf16 MFMA GEMM: C = A[M,K]bf16 * W[N,K]bf16^T ----------------
template<int BN, int WM, int WN, int NST, bool TC>
__global__ __launch_bounds__(256, 2) void gemm_mfma(const ushort_t* __restrict__ A,
        const ushort_t* __restrict__ W, float* __restrict__ C, int K, int ldC) {
    constexpr int FM = 128 / (WM * 16);
    constexpr int FN = BN / (WN * 16);
    __shared__ ushort_t sA[128 * 32];
    __shared__ ushort_t sB[BN * 32];
    const int t = threadIdx.x;
    const int wave = t >> 6, lane = t & 63;
    const int lr = lane & 15, lq = lane >> 4;
    const int wr = wave / WN, wc = wave % WN;
    const int m0 = blockIdx.x * 128, n0 = blockIdx.y * BN;
    const int wbase = t & ~63;

    f32x4 acc[FM][FN];
    #pragma unroll
    for (int i = 0; i < FM; i++)
        #pragma unroll
        for (int j = 0; j < FN; j++) acc[i][j] = f32x4{0.f, 0.f, 0.f, 0.f};

    for (int k0 = 0; k0 < K; k0 += 32) {
        __syncthreads();
        #pragma unroll
        for (int c = 0; c < 2; c++) {           // A: 512 slots
            int s = c * 256 + t;
            int row = s >> 2;
            int quad = (s & 3) ^ ((row >> 1) & 3);
            load_lds16(A + (size_t)(m0 + row) * K + k0 + quad * 8,
                       sA + (size_t)(c * 256 + wbase) * 8);
        }
        #pragma unroll
        for (int c = 0; c < BN * 4 / 256; c++) { // B: BN*4 slots
            int s = c * 256 + t;
            int row = s >> 2;
            int quad = (s & 3) ^ ((row >> 1) & 3);
            load_lds16(W + (size_t)(n0 + row) * K + k0 + quad * 8,
                       sB + (size_t)(c * 256 + wbase) * 8);
        }
        __syncthreads();
        bf16x8 af[FM], bfr[FN];
        #pragma unroll
        for (int i = 0; i < FM; i++) {
            int row = wr * FM * 16 + i * 16 + lr;
            int slot = (row << 2) | (lq ^ ((row >> 1) & 3));
            af[i] = *(const bf16x8*)&sA[(size_t)slot * 8];
        }
        #pragma unroll
        for (int j = 0; j < FN; j++) {
            int row = wc * FN * 16 + j * 16 + lr;
            int slot = (row << 2) | (lq ^ ((row >> 1) & 3));
            bfr[j] = *(const bf16x8*)&sB[(size_t)slot * 8];
        }
        #pragma unroll
        for (int i = 0; i < FM; i++)
            #pragma unroll
            for (int j = 0; j < FN; j++)
                acc[i][j] = __builtin_amdgcn_mfma_f32_16x16x32_bf16(af[i], bfr[j], acc[i][j], 0, 0, 0);
    }
    // C/D layout: col = lane&15, row = (lane>>4)*4 + reg
    int crow0 = m0 + wr * FM * 16 + lq * 4;
    int ccol0 = n0 + wc * FN * 16 + lr;
    if constexpr (TC) {
        #pragma unroll
        for (int i = 0; i < FM; i++) {
            int m = crow0 + i * 16;
            int bb = m / 196, l = m % 196;
            #pragma unroll
            for (int j = 0; j < FN; j++) {
                int col = ccol0 + j * 16;
                if (col < 44) {
                    float4 v = {acc[i][j][0], acc[i][j][1], acc[i][j][2], acc[i][j][3]};
                    *(float4*)(C + (size_t)bb * XDP + (size_t)col * 196 + l) = v;
                }
            }
        }
    } else {
        #pragma unroll
        for (int i = 0; i < FM; i++)
            #pragma unroll
            for (int j = 0; j < FN; j++) {
                if (wc * FN + j >= NST) continue;
                float* cp = C + (size_t)(crow0 + i * 16) * ldC + ccol0 + j * 16;
                #pragma unroll
                for (int r = 0; r < 4; r++) cp[(size_t)r * ldC] = acc[i][j][r];
            }
    }
}

// ---------------- Patch-embed bf16 MFMA with im2col A-loader ----------------
__global__ __launch_bounds__(256, 2) void gemm_patch_mfma(const ushort_t* __restrict__ Xbf,
        const ushort_t* __restrict__ Wbf, const float* __restrict__ bias, float* __restrict__ C) {
    constexpr int FM = 2, FN = 4;
    __shared__ ushort_t sA[128 * 32];
    __shared__ ushort_t sB[64 * 32];
    const int t = threadIdx.x;
    const int wave = t >> 6, lane = t & 63;
    const int lr = lane & 15, lq = lane >> 4;
    const int m0 = blockIdx.x * 128, n0 = blockIdx.y * 64;
    const int wbase = t & ~63;

    const ushort_t* abase[2];
    int aquad[2];
    #pragma unroll
    for (int c = 0; c < 2; c++) {
        int s = c * 256 + t;
        int row = s >> 2;
        aquad[c] = (s & 3) ^ ((row >> 1) & 3);
        int m = m0 + row;
        int b = m / 196, r = m % 196, py = r / 14, px = r % 14;
        abase[c] = Xbf + (size_t)b * 150528 + py * 3584 + px * 16;
    }
    int brow = t >> 2;
    int bquad = (t & 3) ^ ((brow >> 1) & 3);
    const ushort_t* bbase = Wbf + (size_t)(n0 + brow) * 768 + bquad * 8;

    f32x4 acc[FM][FN];
    #pragma unroll
    for (int i = 0; i < FM; i++)
        #pragma unroll
        for (int j = 0; j < FN; j++) acc[i][j] = f32x4{0.f, 0.f, 0.f, 0.f};

    for (int k0 = 0; k0 < 768; k0 += 32) {
        __syncthreads();
        #pragma unroll
        for (int c = 0; c < 2; c++) {
            int k = k0 + aquad[c] * 8;
            int ci = k >> 8, ky = (k >> 4) & 15, kx0 = k & 15;
            load_lds16(abase[c] + ci * 50176 + ky * 224 + kx0,
                       sA + (size_t)(c * 256 + wbase) * 8);
        }
        load_lds16(bbase + k0, sB + (size_t)wbase * 8);
        __syncthreads();
        bf16x8 af[FM], bfr[FN];
        #pragma unroll
        for (int i = 0; i < FM; i++) {
            int row = wave * FM * 16 + i * 16 + lr;
            int slot = (row << 2) | (lq ^ ((row >> 1) & 3));
            af[i] = *(const bf16x8*)&sA[(size_t)slot * 8];
        }
        #pragma unroll
        for (int j = 0; j < FN; j++) {
            int row = j * 16 + lr;
            int slot = (row << 2) | (lq ^ ((row >> 1) & 3));
            bfr[j] = *(const bf16x8*)&sB[(size_t)slot * 8];
        }
        #pragma unroll
        for (int i = 0; i < FM; i++)
            #pragma unroll
            for (int j = 0; j < FN; j++)
                acc[i][j] = __builtin_amdgcn_mfma_f32_16x16x32_bf16(af[i], bfr[j], acc[i][j], 0, 0, 0);
    }
    int crow0 = m0 + wave * FM * 16 + lq * 4;
    int ccol0 = n0 + lr;
    #pragma unroll
    for (int i = 0; i < FM; i++)
        #pragma unroll
        for (int j = 0; j < FN; j++) {
            int col = ccol0 + j * 16;
            float bv = bias[col];
            float* cp = C + (size_t)(crow0 + i * 16) * DM + col;
            #pragma unroll
            for (int r = 0; r < 4; r++) cp[(size_t)r * DM] = acc[i][j][r] + bv;
        }
}

// ---------------- Small fp32 GEMM (head only) ----------------
template<bool BIAS>
__global__ __launch_bounds__(256, 2) void gemm64(const float* __restrict__ A,
        const float* __restrict__ W, const float* __restrict__ bias,
        float* __restrict__ C, int M, int N, int K) {
    __shared__ float As[32][68];
    __shared__ float Ws[32][68];
    int t = threadIdx.x;
    int m0 = blockIdx.x * 64, n0 = blockIdx.y * 64;
    int lr = t >> 2, lk = (t & 3) * 4;
    int am = m0 + lr; bool avld = am < M;
    const float* Ap = A + (size_t)(avld ? am : 0) * K + lk;
    int wn = n0 + lr; bool wv = wn < N;
    const float* Wp = W + (size_t)(wv ? wn : 0) * K + lk;
    int tm = (t >> 4) * 4, tn = (t & 15) * 4;
    float acc[4][4];
    #pragma unroll
    for (int i = 0; i < 4; i++)
        #pragma unroll
        for (int j = 0; j < 4; j++) acc[i][j] = 0.f;

    for (int k0 = 0; k0 < K; k0 += 32) {
        float4 a0 = make_float4(0.f, 0.f, 0.f, 0.f), a1 = a0, w0 = a0, w1 = a0;
        if (avld) { a0 = *(const float4*)(Ap + k0); a1 = *(const float4*)(Ap + k0 + 16); }
        if (wv)   { w0 = *(const float4*)(Wp + k0); w1 = *(const float4*)(Wp + k0 + 16); }
        __syncthreads();
        As[lk + 0][lr] = a0.x; As[lk + 1][lr] = a0.y; As[lk + 2][lr] = a0.z; As[lk + 3][lr] = a0.w;
        As[lk + 16][lr] = a1.x; As[lk + 17][lr] = a1.y; As[lk + 18][lr] = a1.z; As[lk + 19][lr] = a1.w;
        Ws[lk + 0][lr] = w0.x; Ws[lk + 1][lr] = w0.y; Ws[lk + 2][lr] = w0.z; Ws[lk + 3][lr] = w0.w;
        Ws[lk + 16][lr] = w1.x; Ws[lk + 17][lr] = w1.y; Ws[lk + 18][lr] = w1.z; Ws[lk + 19][lr] = w1.w;
        __syncthreads();
        #pragma unroll
        for (int kk = 0; kk < 32; kk++) {
            float4 x0 = *(const float4*)&As[kk][tm];
            float4 y0 = *(const float4*)&Ws[kk][tn];
            float av[4] = {x0.x, x0.y, x0.z, x0.w};
            float bv[4] = {y0.x, y0.y, y0.z, y0.w};
            #pragma unroll
            for (int i = 0; i < 4; i++)
                #pragma unroll
                for (int j = 0; j < 4; j++) acc[i][j] = fmaf(av[i], bv[j], acc[i][j]);
        }
    }
    #pragma unroll
    for (int i = 0; i < 4; i++) {
        int m = m0 + tm + i;
        if (m >= M) continue;
        float* cr = C + (size_t)m * N;
        int n = n0 + tn;
        if (n < N) {
            float4 v = {acc[i][0], acc[i][1], acc[i][2], acc[i][3]};
            if (BIAS) { v.x += bias[n]; v.y += bias[n + 1]; v.z += bias[n + 2]; v.w += bias[n + 3]; }
            *(float4*)(cr + n) = v;
        }
    }
}

// ---------------- depthwise causal conv(4) + SiLU -> bf16 ----------------
__global__ void conv_silu_kernel(const float* __restrict__ xz, const float* __restrict__ cw,
                                 const float* __restrict__ cb, ushort_t* __restrict__ xcbf) {
    int idx = blockIdx.x * 256 + threadIdx.x;
    if (idx >= MROWS * DI) return;
    int e = idx % DI; int bl = idx / DI; int l = bl % SEQL; int b = bl / SEQL;
    const float* base = xz + (size_t)(b * SEQL) * 768 + e;
    float w0 = cw[e * 4], w1 = cw[e * 4 + 1], w2 = cw[e * 4 + 2], w3 = cw[e * 4 + 3];
    float acc = cb[e];
    if (l >= 3) acc = fmaf(base[(size_t)(l - 3) * 768], w0, acc);
    if (l >= 2) acc = fmaf(base[(size_t)(l - 2) * 768], w1, acc);
    if (l >= 1) acc = fmaf(base[(size_t)(l - 1) * 768], w2, acc);
    acc = fmaf(base[(size_t)l * 768], w3, acc);
    xcbf[idx] = f2bf(acc * sigmoidf_(acc));
}

// ---------------- wave-parallel chunked selective scan, v5 ----------------
// grid (64 b, 48 e-groups), block 512 = 8 waves; wave handles e = eg*8+wave.
// One 34.5 KB x_dbl plane serves 8 waves. Wave-uniform Av[16]/wdt[12] live in
// per-wave LDS (broadcast reads) instead of VGPRs; launch_bounds(512,4)
// (VGPR cap 128) so nothing spills to scratch (round-8 lesson: WRITE_SIZE
// 114 MB at bounds(512,5)/48 VGPR was spill traffic).
__global__ __launch_bounds__(512, 4) void scan_kernel(const float* __restrict__ xdt,
        const ushort_t* __restrict__ xcbf, const float* __restrict__ xz,
        const float* __restrict__ dtw, const float* __restrict__ dtb,
        const float* __restrict__ a_log, const float* __restrict__ Dp, ushort_t* __restrict__ y) {
    __shared__ float sd[44 * 196];       // 34496 B
    __shared__ ushort_t zs[8 * 200];     // [e_off][l] bf16
    __shared__ ushort_t xcs[8 * 200];    // [e_off][l] bf16
    __shared__ ushort_t ys[8 * 200];     // [e_off][l] bf16
    __shared__ float avs[8][16];         // per-wave -exp(a_log)
    __shared__ float wdts[8][16];        // per-wave dt_w row (12 used)
    const int b = blockIdx.x, eg = blockIdx.y;
    const int tid = threadIdx.x;
    const int wave = tid >> 6, lane = tid & 63;
    const int e = eg * 8 + wave;

    {   // stage x_dbl_t plane (contiguous float4 copy)
        const float4* src4 = (const float4*)(xdt + (size_t)b * XDP);
        float4* sd4 = (float4*)sd;
        for (int i = tid; i < XDP / 4; i += 512) sd4[i] = src4[i];
    }
    if (lane < DS) avs[wave][lane] = -__expf(a_log[(size_t)e * DS + lane]);
    if (lane >= 16 && lane < 16 + DR) wdts[wave][lane - 16] = dtw[(size_t)e * DR + (lane - 16)];
    if (tid < 196) {  // stage xc and z (bf16) for the 8 e's
        int l = tid;
        const ushort_t* xp = xcbf + (size_t)(b * SEQL + l) * DI + eg * 8;
        ushort4 xq0 = *(const ushort4*)xp;
        ushort4 xq1 = *(const ushort4*)(xp + 4);
        const float* zp = xz + (size_t)(b * SEQL + l) * 768 + DI + eg * 8;
        float4 zq0 = *(const float4*)zp;
        float4 zq1 = *(const float4*)(zp + 4);
        xcs[0 * 200 + l] = xq0.x; xcs[1 * 200 + l] = xq0.y;
        xcs[2 * 200 + l] = xq0.z; xcs[3 * 200 + l] = xq0.w;
        xcs[4 * 200 + l] = xq1.x; xcs[5 * 200 + l] = xq1.y;
        xcs[6 * 200 + l] = xq1.z; xcs[7 * 200 + l] = xq1.w;
        zs[0 * 200 + l] = f2bf(zq0.x); zs[1 * 200 + l] = f2bf(zq0.y);
        zs[2 * 200 + l] = f2bf(zq0.z); zs[3 * 200 + l] = f2bf(zq0.w);
        zs[4 * 200 + l] = f2bf(zq1.x); zs[5 * 200 + l] = f2bf(zq1.y);
        zs[6 * 200 + l] = f2bf(zq1.z); zs[7 * 200 + l] = f2bf(zq1.w);
    }
    __syncthreads();

    const float db = dtb[e], Dv = Dp[e];
    const bool act = lane < 49;
    const int lbase = act ? lane * 4 : 0;

    // delta = softplus(dt_row . wdt + db), 4 l's at once
    f32x4 dt4 = {db, db, db, db};
    #pragma unroll
    for (int k = 0; k < DR; k++) {
        f32x4 r = *(const f32x4*)&sd[k * 196 + lbase];
        dt4 += r * wdts[wave][k];
    }
    f32x4 d4;
    #pragma unroll
    for (int s = 0; s < 4; s++) {
        float v = dt4[s];
        d4[s] = (v > 20.f) ? v : log1pf(__expf(v));
    }
    ushort4 xcq = *(const ushort4*)&xcs[wave * 200 + lbase];
    f32x4 xcv4 = {bf2f(xcq.x), bf2f(xcq.y), bf2f(xcq.z), bf2f(xcq.w)};
    ushort4 zq = *(const ushort4*)&zs[wave * 200 + lbase];
    f32x4 zv4 = {bf2f(zq.x), bf2f(zq.y), bf2f(zq.z), bf2f(zq.w)};
    f32x4 du4 = d4 * xcv4;

    // pass 1: local affine transform per lane-chunk
    float P[DS], h[DS];
    #pragma unroll
    for (int n = 0; n < DS; n++) { P[n] = 1.f; h[n] = 0.f; }
    if (act) {
        #pragma unroll
        for (int n = 0; n < DS; n++) {
            float Avn = avs[wave][n];
            f32x4 Bn = *(const f32x4*)&sd[(12 + n) * 196 + lbase];
            float hn = 0.f, Pn = 1.f;
            #pragma unroll
            for (int s = 0; s < 4; s++) {
                float dA = __expf(d4[s] * Avn);
                hn = fmaf(hn, dA, du4[s] * Bn[s]);
                Pn *= dA;
            }
            P[n] = Pn; h[n] = hn;
        }
    }

    // Kogge-Stone inclusive scan of affine maps across lanes
    #pragma unroll
    for (int off = 1; off < 64; off <<= 1) {
        #pragma unroll
        for (int n = 0; n < DS; n++) {
            float Pp = __shfl_up(P[n], off);
            float Hp = __shfl_up(h[n], off);
            if (lane >= off) {
                h[n] = fmaf(P[n], Hp, h[n]);
                P[n] *= Pp;
            }
        }
    }
    #pragma unroll
    for (int n = 0; n < DS; n++) {  // exclusive: incoming state
        float Hp = __shfl_up(h[n], 1);
        h[n] = (lane == 0) ? 0.f : Hp;
    }

    // pass 2: replay with correct incoming state; y = h.C + xc*D, gate silu(z)
    if (act) {
        f32x4 acc4 = {0.f, 0.f, 0.f, 0.f};
        #pragma unroll
        for (int n = 0; n < DS; n++) {
            float Avn = avs[wave][n];
            f32x4 Bn = *(const f32x4*)&sd[(12 + n) * 196 + lbase];
            f32x4 Cn = *(const f32x4*)&sd[(28 + n) * 196 + lbase];
            float hn = h[n];
            #pragma unroll
            for (int s = 0; s < 4; s++) {
                float dA = __expf(d4[s] * Avn);
                hn = fmaf(hn, dA, du4[s] * Bn[s]);
                acc4[s] = fmaf(hn, Cn[s], acc4[s]);
            }
        }
        ushort_t* yw = &ys[wave * 200 + lbase];
        #pragma unroll
        for (int s = 0; s < 4; s++) {
            float yv = fmaf(xcv4[s], Dv, acc4[s]);
            float zv = zv4[s];
            yw[s] = f2bf(yv * zv * sigmoidf_(zv));
        }
    }
    __syncthreads();
    if (tid < 196) {  // cooperative store of y for the 8 e's
        int l = tid;
        ushort4 o0, o1;
        o0.x = ys[0 * 200 + l]; o0.y = ys[1 * 200 + l];
        o0.z = ys[2 * 200 + l]; o0.w = ys[3 * 200 + l];
        o1.x = ys[4 * 200 + l]; o1.y = ys[5 * 200 + l];
        o1.z = ys[6 * 200 + l]; o1.w = ys[7 * 200 + l];
        ushort_t* yp = y + (size_t)(b * SEQL + l) * DI + eg * 8;
        *(ushort4*)yp = o0;
        *(ushort4*)(yp + 4) = o1;
    }
}

// ---------------- mean over L ----------------
__global__ void pool_kernel(const float* __restrict__ normed, float* __restrict__ pooled) {
    int b = blockIdx.x, d = threadIdx.x;
    float s = 0.f;
    for (int l = 0; l < SEQL; l++) s += normed[(size_t)(b * SEQL + l) * DM + d];
    pooled[b * DM + d] = s * (1.f / 196.f);
}

extern "C" void kernel_launch(void* const* d_in, const int* in_sizes, int n_in,
                              void* d_out, int out_size, void* d_ws, size_t ws_size,
                              hipStream_t stream) {
    const float* x       = (const float*)d_in[0];
    const float* patch_w = (const float*)d_in[1];
    const float* patch_b = (const float*)d_in[2];
    const float* norm_w  = (const float*)d_in[3];
    const float* norm_b  = (const float*)d_in[4];
    const float* in_w    = (const float*)d_in[5];
    const float* conv_w  = (const float*)d_in[6];
    const float* conv_b  = (const float*)d_in[7];
    const float* xp_w    = (const float*)d_in[8];
    const float* dt_w    = (const float*)d_in[9];
    const float* dt_b    = (const float*)d_in[10];
    const float* A_log   = (const float*)d_in[11];
    const float* Dp      = (const float*)d_in[12];
    const float* out_w   = (const float*)d_in[13];
    const float* normf_w = (const float*)d_in[14];
    const float* normf_b = (const float*)d_in[15];
    const float* head_w  = (const float*)d_in[16];
    const float* head_b  = (const float*)d_in[17];

    float* ws = (float*)d_ws;
    // Disjoint layout (only alias: x_bf over xcbf+y_bf, round-4-validated).
    float* residual     = ws;                          // [0, 2408448)
    float* hidden       = ws + 2408448;                // [2408448, 4816896)
    float* xz           = ws + 4816896;                // [4816896, 14450688)
    ushort_t* xcbf      = (ushort_t*)(ws + 14450688);  // [14450688, 16859136)
    ushort_t* y_bf      = (ushort_t*)(ws + 16859136);  // [16859136, 19267584)
    ushort_t* x_bf      = (ushort_t*)(ws + 14450688);  // alias, dead before layer-0 conv
    ushort_t* normed_bf = (ushort_t*)(ws + 19267584);  // [19267584, 20471808)
    float* xdbl_t       = ws + 20471808;               // [20471808, 21023744)
    float* pooled       = ws + 21023744;               // [21023744, 21036032)
    ushort_t* in_w_bf   = (ushort_t*)(ws + 21036032);  // [21036032, 22805504)
    ushort_t* out_w_bf  = (ushort_t*)(ws + 22805504);  // [22805504, 23690240)
    ushort_t* xp_w_bf   = (ushort_t*)(ws + 23690240);  // [23690240, 23985152)
    ushort_t* patch_w_bf= (ushort_t*)(ws + 23985152);  // [23985152, 24058880)
    // end 24,058,880 floats = 96.2 MB

    hipMemsetAsync(residual, 0, (size_t)2408448 * sizeof(float), stream);

    f2bf4_kernel<<<3456, 256, 0, stream>>>(in_w, in_w_bf, 884736);
    f2bf4_kernel<<<1728, 256, 0, stream>>>(out_w, out_w_bf, 442368);
    f2bf4_kernel<<<144, 256, 0, stream>>>(patch_w, patch_w_bf, 36864);
    f2bf4_kernel<<<9408, 256, 0, stream>>>(x, x_bf, 2408448);
    xp_pad_kernel<<<2304, 256, 0, stream>>>(xp_w, xp_w_bf);

    gemm_patch_mfma<<<dim3(98, 3), 256, 0, stream>>>(x_bf, patch_w_bf, patch_b, hidden);

    for (int d = 0; d < DEPTH; ++d) {
        ln_kernel<true><<<3136, 256, 0, stream>>>(residual, hidden, norm_w + d * DM,
                                                  norm_b + d * DM, normed_bf);
        gemm_mfma<192, 2, 2, 12, false><<<dim3(98, 4), 256, 0, stream>>>(normed_bf,
                in_w_bf + (size_t)d * 768 * 192, xz, 192, 768);
        conv_silu_kernel<<<18816, 256, 0, stream>>>(xz, conv_w + d * DI * 4, conv_b + d * DI, xcbf);
        // x_proj -> transposed x_dbl [b][44][196]
        gemm_mfma<64, 4, 1, 3, true><<<dim3(98, 1), 256, 0, stream>>>(xcbf,
                xp_w_bf + (size_t)d * 64 * 384, xdbl_t, 384, 196);
        scan_kernel<<<dim3(64, 48), 512, 0, stream>>>(xdbl_t, xcbf, xz, dt_w + d * DI * DR,
                dt_b + d * DI, A_log + d * DI * DS, Dp + d * DI, y_bf);
        gemm_mfma<64, 4, 1, 4, false><<<dim3(98, 3), 256, 0, stream>>>(y_bf,
                out_w_bf + (size_t)d * 192 * 384, hidden, 384, 192);
    }

    ln_kernel<false><<<3136, 256, 0, stream>>>(residual, hidden, normf_w, normf_b, xz);
    pool_kernel<<<64, 192, 0, stream>>>(xz, pooled);
    gemm64<true><<<dim3(1, 16), 256, 0, stream>>>(pooled, head_w, head_b, (float*)d_out, 64, 1000, 192);
}

// Round 11
// 3534.897 us; speedup vs baseline: 1.2351x; 1.0637x over previous
//
#include <hip/hip_runtime.h>
#include <math.h>

// VisionMamba forward. Round 11: round-10 scan v6 with compile fix —
// __exp2f -> __builtin_amdgcn_exp2f (native v_exp_f32). Register diet:
// xc/z re-read from LDS after Kogge-Stone; Av carries log2e; fast softplus.
// B=64, L=196, D_MODEL=192, D_INNER=384, D_STATE=16, DT_RANK=12, DEPTH=24.

#define DEPTH 24
#define DM 192
#define DI 384
#define DS 16
#define DR 12
#define SEQL 196
#define BATCH 64
#define MROWS (BATCH*SEQL)   // 12544
#define XDP 8624             // x_dbl_t per-b plane: 44*196 floats
#define LOG2E 1.44269504088896340736f

typedef unsigned short ushort_t;
typedef __bf16 bf16x8 __attribute__((ext_vector_type(8)));
typedef float f32x4 __attribute__((ext_vector_type(4)));

__device__ __forceinline__ float sigmoidf_(float x) { return 1.f / (1.f + __expf(-x)); }

__device__ __forceinline__ ushort_t f2bf(float f) {  // RNE fp32->bf16
    union { float f; unsigned u; } c; c.f = f;
    unsigned u = c.u;
    return (ushort_t)((u + 0x7FFFu + ((u >> 16) & 1u)) >> 16);
}
__device__ __forceinline__ float bf2f(ushort_t u) {
    union { unsigned u; float f; } c; c.u = ((unsigned)u) << 16;
    return c.f;
}

__device__ __forceinline__ void load_lds16(const ushort_t* g, ushort_t* l) {
    __builtin_amdgcn_global_load_lds((__attribute__((address_space(1))) void*)g,
                                     (__attribute__((address_space(3))) void*)l, 16, 0, 0);
}

// ---------------- fp32 -> bf16 bulk convert, 4 elems/thread ----------------
__global__ void f2bf4_kernel(const float* __restrict__ src, ushort_t* __restrict__ dst, int n4) {
    int i = blockIdx.x * 256 + threadIdx.x;
    if (i >= n4) return;
    float4 v = ((const float4*)src)[i];
    union { ushort_t s[4]; uint2 u; } o;
    o.s[0] = f2bf(v.x); o.s[1] = f2bf(v.y); o.s[2] = f2bf(v.z); o.s[3] = f2bf(v.w);
    ((uint2*)dst)[i] = o.u;
}

// xp_w [24][44][384] -> padded bf16 [24][64][384], rows 44..63 = 0
__global__ void xp_pad_kernel(const float* __restrict__ src, ushort_t* __restrict__ dst) {
    int i = blockIdx.x * 256 + threadIdx.x;
    if (i >= DEPTH * 64 * 384) return;
    int col = i % 384, row = (i / 384) & 63, d = i / (384 * 64);
    float v = (row < 44) ? src[(size_t)d * 44 * 384 + row * 384 + col] : 0.f;
    dst[i] = f2bf(v);
}

// ---------------- residual += hidden; out = LayerNorm(residual) ----------------
template<bool BF>
__global__ void ln_kernel(float* __restrict__ residual, const float* __restrict__ hidden,
                          const float* __restrict__ w, const float* __restrict__ b,
                          void* __restrict__ out_) {
    int wave = threadIdx.x >> 6, lane = threadIdx.x & 63;
    int row = blockIdx.x * 4 + wave;
    float* rr = residual + (size_t)row * DM;
    const float* hr = hidden + (size_t)row * DM;
    float v0 = rr[lane]       + hr[lane];
    float v1 = rr[lane + 64]  + hr[lane + 64];
    float v2 = rr[lane + 128] + hr[lane + 128];
    rr[lane] = v0; rr[lane + 64] = v1; rr[lane + 128] = v2;
    float s = v0 + v1 + v2;
    #pragma unroll
    for (int off = 32; off > 0; off >>= 1) s += __shfl_down(s, off);
    float mean = __shfl(s, 0) * (1.f / DM);
    float d0 = v0 - mean, d1 = v1 - mean, d2 = v2 - mean;
    float q = d0 * d0 + d1 * d1 + d2 * d2;
    #pragma unroll
    for (int off = 32; off > 0; off >>= 1) q += __shfl_down(q, off);
    float rstd = rsqrtf(__shfl(q, 0) * (1.f / DM) + 1e-5f);
    float o0 = d0 * rstd * w[lane]       + b[lane];
    float o1 = d1 * rstd * w[lane + 64]  + b[lane + 64];
    float o2 = d2 * rstd * w[lane + 128] + b[lane + 128];
    if constexpr (BF) {
        ushort_t* o = (ushort_t*)out_ + (size_t)row * DM;
        o[lane] = f2bf(o0); o[lane + 64] = f2bf(o1); o[lane + 128] = f2bf(o2);
    } else {
        float* o = (float*)out_ + (size_t)row * DM;
        o[lane] = o0; o[lane + 64] = o1; o[lane + 128] = o2;
    }
}

// ---------------- bf16 MFMA GEMM: C = A[M,K]bf16 * W[N,K]bf16^T ----------------
template<int BN, int WM, int WN, int NST, bool TC>
__global__ __launch_bounds__(256, 2) void gemm_mfma(const ushort_t* __restrict__ A,
        const ushort_t* __restrict__ W, float* __restrict__ C, int K, int ldC) {
    constexpr int FM = 128 / (WM * 16);
    constexpr int FN = BN / (WN * 16);
    __shared__ ushort_t sA[128 * 32];
    __shared__ ushort_t sB[BN * 32];
    const int t = threadIdx.x;
    const int wave = t >> 6, lane = t & 63;
    const int lr = lane & 15, lq = lane >> 4;
    const int wr = wave / WN, wc = wave % WN;
    const int m0 = blockIdx.x * 128, n0 = blockIdx.y * BN;
    const int wbase = t & ~63;

    f32x4 acc[FM][FN];
    #pragma unroll
    for (int i = 0; i < FM; i++)
        #pragma unroll
        for (int j = 0; j < FN; j++) acc[i][j] = f32x4{0.f, 0.f, 0.f, 0.f};

    for (int k0 = 0; k0 < K; k0 += 32) {
        __syncthreads();
        #pragma unroll
        for (int c = 0; c < 2; c++) {           // A: 512 slots
            int s = c * 256 + t;
            int row = s >> 2;
            int quad = (s & 3) ^ ((row >> 1) & 3);
            load_lds16(A + (size_t)(m0 + row) * K + k0 + quad * 8,
                       sA + (size_t)(c * 256 + wbase) * 8);
        }
        #pragma unroll
        for (int c = 0; c < BN * 4 / 256; c++) { // B: BN*4 slots
            int s = c * 256 + t;
            int row = s >> 2;
            int quad = (s & 3) ^ ((row >> 1) & 3);
            load_lds16(W + (size_t)(n0 + row) * K + k0 + quad * 8,
                       sB + (size_t)(c * 256 + wbase) * 8);
        }
        __syncthreads();
        bf16x8 af[FM], bfr[FN];
        #pragma unroll
        for (int i = 0; i < FM; i++) {
            int row = wr * FM * 16 + i * 16 + lr;
            int slot = (row << 2) | (lq ^ ((row >> 1) & 3));
            af[i] = *(const bf16x8*)&sA[(size_t)slot * 8];
        }
        #pragma unroll
        for (int j = 0; j < FN; j++) {
            int row = wc * FN * 16 + j * 16 + lr;
            int slot = (row << 2) | (lq ^ ((row >> 1) & 3));
            bfr[j] = *(const bf16x8*)&sB[(size_t)slot * 8];
        }
        #pragma unroll
        for (int i = 0; i < FM; i++)
            #pragma unroll
            for (int j = 0; j < FN; j++)
                acc[i][j] = __builtin_amdgcn_mfma_f32_16x16x32_bf16(af[i], bfr[j], acc[i][j], 0, 0, 0);
    }
    // C/D layout: col = lane&15, row = (lane>>4)*4 + reg
    int crow0 = m0 + wr * FM * 16 + lq * 4;
    int ccol0 = n0 + wc * FN * 16 + lr;
    if constexpr (TC) {
        #pragma unroll
        for (int i = 0; i < FM; i++) {
            int m = crow0 + i * 16;
            int bb = m / 196, l = m % 196;
            #pragma unroll
            for (int j = 0; j < FN; j++) {
                int col = ccol0 + j * 16;
                if (col < 44) {
                    float4 v = {acc[i][j][0], acc[i][j][1], acc[i][j][2], acc[i][j][3]};
                    *(float4*)(C + (size_t)bb * XDP + (size_t)col * 196 + l) = v;
                }
            }
        }
    } else {
        #pragma unroll
        for (int i = 0; i < FM; i++)
            #pragma unroll
            for (int j = 0; j < FN; j++) {
                if (wc * FN + j >= NST) continue;
                float* cp = C + (size_t)(crow0 + i * 16) * ldC + ccol0 + j * 16;
                #pragma unroll
                for (int r = 0; r < 4; r++) cp[(size_t)r * ldC] = acc[i][j][r];
            }
    }
}

// ---------------- Patch-embed bf16 MFMA with im2col A-loader ----------------
__global__ __launch_bounds__(256, 2) void gemm_patch_mfma(const ushort_t* __restrict__ Xbf,
        const ushort_t* __restrict__ Wbf, const float* __restrict__ bias, float* __restrict__ C) {
    constexpr int FM = 2, FN = 4;
    __shared__ ushort_t sA[128 * 32];
    __shared__ ushort_t sB[64 * 32];
    const int t = threadIdx.x;
    const int wave = t >> 6, lane = t & 63;
    const int lr = lane & 15, lq = lane >> 4;
    const int m0 = blockIdx.x * 128, n0 = blockIdx.y * 64;
    const int wbase = t & ~63;

    const ushort_t* abase[2];
    int aquad[2];
    #pragma unroll
    for (int c = 0; c < 2; c++) {
        int s = c * 256 + t;
        int row = s >> 2;
        aquad[c] = (s & 3) ^ ((row >> 1) & 3);
        int m = m0 + row;
        int b = m / 196, r = m % 196, py = r / 14, px = r % 14;
        abase[c] = Xbf + (size_t)b * 150528 + py * 3584 + px * 16;
    }
    int brow = t >> 2;
    int bquad = (t & 3) ^ ((brow >> 1) & 3);
    const ushort_t* bbase = Wbf + (size_t)(n0 + brow) * 768 + bquad * 8;

    f32x4 acc[FM][FN];
    #pragma unroll
    for (int i = 0; i < FM; i++)
        #pragma unroll
        for (int j = 0; j < FN; j++) acc[i][j] = f32x4{0.f, 0.f, 0.f, 0.f};

    for (int k0 = 0; k0 < 768; k0 += 32) {
        __syncthreads();
        #pragma unroll
        for (int c = 0; c < 2; c++) {
            int k = k0 + aquad[c] * 8;
            int ci = k >> 8, ky = (k >> 4) & 15, kx0 = k & 15;
            load_lds16(abase[c] + ci * 50176 + ky * 224 + kx0,
                       sA + (size_t)(c * 256 + wbase) * 8);
        }
        load_lds16(bbase + k0, sB + (size_t)wbase * 8);
        __syncthreads();
        bf16x8 af[FM], bfr[FN];
        #pragma unroll
        for (int i = 0; i < FM; i++) {
            int row = wave * FM * 16 + i * 16 + lr;
            int slot = (row << 2) | (lq ^ ((row >> 1) & 3));
            af[i] = *(const bf16x8*)&sA[(size_t)slot * 8];
        }
        #pragma unroll
        for (int j = 0; j < FN; j++) {
            int row = j * 16 + lr;
            int slot = (row << 2) | (lq ^ ((row >> 1) & 3));
            bfr[j] = *(const bf16x8*)&sB[(size_t)slot * 8];
        }
        #pragma unroll
        for (int i = 0; i < FM; i++)
            #pragma unroll
            for (int j = 0; j < FN; j++)
                acc[i][j] = __builtin_amdgcn_mfma_f32_16x16x32_bf16(af[i], bfr[j], acc[i][j], 0, 0, 0);
    }
    int crow0 = m0 + wave * FM * 16 + lq * 4;
    int ccol0 = n0 + lr;
    #pragma unroll
    for (int i = 0; i < FM; i++)
        #pragma unroll
        for (int j = 0; j < FN; j++) {
            int col = ccol0 + j * 16;
            float bv = bias[col];
            float* cp = C + (size_t)(crow0 + i * 16) * DM + col;
            #pragma unroll
            for (int r = 0; r < 4; r++) cp[(size_t)r * DM] = acc[i][j][r] + bv;
        }
}

// ---------------- Small fp32 GEMM (head only) ----------------
template<bool BIAS>
__global__ __launch_bounds__(256, 2) void gemm64(const float* __restrict__ A,
        const float* __restrict__ W, const float* __restrict__ bias,
        float* __restrict__ C, int M, int N, int K) {
    __shared__ float As[32][68];
    __shared__ float Ws[32][68];
    int t = threadIdx.x;
    int m0 = blockIdx.x * 64, n0 = blockIdx.y * 64;
    int lr = t >> 2, lk = (t & 3) * 4;
    int am = m0 + lr; bool avld = am < M;
    const float* Ap = A + (size_t)(avld ? am : 0) * K + lk;
    int wn = n0 + lr; bool wv = wn < N;
    const float* Wp = W + (size_t)(wv ? wn : 0) * K + lk;
    int tm = (t >> 4) * 4, tn = (t & 15) * 4;
    float acc[4][4];
    #pragma unroll
    for (int i = 0; i < 4; i++)
        #pragma unroll
        for (int j = 0; j < 4; j++) acc[i][j] = 0.f;

    for (int k0 = 0; k0 < K; k0 += 32) {
        float4 a0 = make_float4(0.f, 0.f, 0.f, 0.f), a1 = a0, w0 = a0, w1 = a0;
        if (avld) { a0 = *(const float4*)(Ap + k0); a1 = *(const float4*)(Ap + k0 + 16); }
        if (wv)   { w0 = *(const float4*)(Wp + k0); w1 = *(const float4*)(Wp + k0 + 16); }
        __syncthreads();
        As[lk + 0][lr] = a0.x; As[lk + 1][lr] = a0.y; As[lk + 2][lr] = a0.z; As[lk + 3][lr] = a0.w;
        As[lk + 16][lr] = a1.x; As[lk + 17][lr] = a1.y; As[lk + 18][lr] = a1.z; As[lk + 19][lr] = a1.w;
        Ws[lk + 0][lr] = w0.x; Ws[lk + 1][lr] = w0.y; Ws[lk + 2][lr] = w0.z; Ws[lk + 3][lr] = w0.w;
        Ws[lk + 16][lr] = w1.x; Ws[lk + 17][lr] = w1.y; Ws[lk + 18][lr] = w1.z; Ws[lk + 19][lr] = w1.w;
        __syncthreads();
        #pragma unroll
        for (int kk = 0; kk < 32; kk++) {
            float4 x0 = *(const float4*)&As[kk][tm];
            float4 y0 = *(const float4*)&Ws[kk][tn];
            float av[4] = {x0.x, x0.y, x0.z, x0.w};
            float bv[4] = {y0.x, y0.y, y0.z, y0.w};
            #pragma unroll
            for (int i = 0; i < 4; i++)
                #pragma unroll
                for (int j = 0; j < 4; j++) acc[i][j] = fmaf(av[i], bv[j], acc[i][j]);
        }
    }
    #pragma unroll
    for (int i = 0; i < 4; i++) {
        int m = m0 + tm + i;
        if (m >= M) continue;
        float* cr = C + (size_t)m * N;
        int n = n0 + tn;
        if (n < N) {
            float4 v = {acc[i][0], acc[i][1], acc[i][2], acc[i][3]};
            if (BIAS) { v.x += bias[n]; v.y += bias[n + 1]; v.z += bias[n + 2]; v.w += bias[n + 3]; }
            *(float4*)(cr + n) = v;
        }
    }
}

// ---------------- depthwise causal conv(4) + SiLU -> bf16 ----------------
__global__ void conv_silu_kernel(const float* __restrict__ xz, const float* __restrict__ cw,
                                 const float* __restrict__ cb, ushort_t* __restrict__ xcbf) {
    int idx = blockIdx.x * 256 + threadIdx.x;
    if (idx >= MROWS * DI) return;
    int e = idx % DI; int bl = idx / DI; int l = bl % SEQL; int b = bl / SEQL;
    const float* base = xz + (size_t)(b * SEQL) * 768 + e;
    float w0 = cw[e * 4], w1 = cw[e * 4 + 1], w2 = cw[e * 4 + 2], w3 = cw[e * 4 + 3];
    float acc = cb[e];
    if (l >= 3) acc = fmaf(base[(size_t)(l - 3) * 768], w0, acc);
    if (l >= 2) acc = fmaf(base[(size_t)(l - 2) * 768], w1, acc);
    if (l >= 1) acc = fmaf(base[(size_t)(l - 1) * 768], w2, acc);
    acc = fmaf(base[(size_t)l * 768], w3, acc);
    xcbf[idx] = f2bf(acc * sigmoidf_(acc));
}

// ---------------- wave-parallel chunked selective scan, v6 ----------------
// grid (64 b, 48 e-groups), block 512 = 8 waves; wave handles e = eg*8+wave.
// Register diet: only P/h/d4/du4 live across the Kogge-Stone; xc/z re-read
// from LDS afterwards. Av carries log2e so dA = exp2 via native v_exp_f32.
__global__ __launch_bounds__(512, 4) void scan_kernel(const float* __restrict__ xdt,
        const ushort_t* __restrict__ xcbf, const float* __restrict__ xz,
        const float* __restrict__ dtw, const float* __restrict__ dtb,
        const float* __restrict__ a_log, const float* __restrict__ Dp, ushort_t* __restrict__ y) {
    __shared__ float sd[44 * 196];       // 34496 B
    __shared__ ushort_t zs[8 * 200];     // [e_off][l] bf16
    __shared__ ushort_t xcs[8 * 200];    // [e_off][l] bf16
    __shared__ ushort_t ys[8 * 200];     // [e_off][l] bf16
    __shared__ float avs[8][16];         // per-wave -exp(a_log)*log2e
    __shared__ float wdts[8][16];        // per-wave dt_w row (12 used)
    const int b = blockIdx.x, eg = blockIdx.y;
    const int tid = threadIdx.x;
    const int wave = tid >> 6, lane = tid & 63;
    const int e = eg * 8 + wave;

    {   // stage x_dbl_t plane (contiguous float4 copy)
        const float4* src4 = (const float4*)(xdt + (size_t)b * XDP);
        float4* sd4 = (float4*)sd;
        for (int i = tid; i < XDP / 4; i += 512) sd4[i] = src4[i];
    }
    if (lane < DS) avs[wave][lane] = -__expf(a_log[(size_t)e * DS + lane]) * LOG2E;
    if (lane >= 16 && lane < 16 + DR) wdts[wave][lane - 16] = dtw[(size_t)e * DR + (lane - 16)];
    if (tid < 196) {  // stage xc and z (bf16) for the 8 e's
        int l = tid;
        const ushort_t* xp = xcbf + (size_t)(b * SEQL + l) * DI + eg * 8;
        ushort4 xq0 = *(const ushort4*)xp;
        ushort4 xq1 = *(const ushort4*)(xp + 4);
        const float* zp = xz + (size_t)(b * SEQL + l) * 768 + DI + eg * 8;
        float4 zq0 = *(const float4*)zp;
        float4 zq1 = *(const float4*)(zp + 4);
        xcs[0 * 200 + l] = xq0.x; xcs[1 * 200 + l] = xq0.y;
        xcs[2 * 200 + l] = xq0.z; xcs[3 * 200 + l] = xq0.w;
        xcs[4 * 200 + l] = xq1.x; xcs[5 * 200 + l] = xq1.y;
        xcs[6 * 200 + l] = xq1.z; xcs[7 * 200 + l] = xq1.w;
        zs[0 * 200 + l] = f2bf(zq0.x); zs[1 * 200 + l] = f2bf(zq0.y);
        zs[2 * 200 + l] = f2bf(zq0.z); zs[3 * 200 + l] = f2bf(zq0.w);
        zs[4 * 200 + l] = f2bf(zq1.x); zs[5 * 200 + l] = f2bf(zq1.y);
        zs[6 * 200 + l] = f2bf(zq1.z); zs[7 * 200 + l] = f2bf(zq1.w);
    }
    __syncthreads();

    const float db = dtb[e];
    const bool act = lane < 49;
    const int lbase = act ? lane * 4 : 0;

    // delta = softplus(dt_row . wdt + db), 4 l's at once
    f32x4 dt4 = {db, db, db, db};
    #pragma unroll
    for (int k = 0; k < DR; k++) {
        f32x4 r = *(const f32x4*)&sd[k * 196 + lbase];
        dt4 += r * wdts[wave][k];
    }
    f32x4 d4;
    #pragma unroll
    for (int s = 0; s < 4; s++) {
        float v = dt4[s];
        d4[s] = (v > 20.f) ? v : __logf(1.f + __expf(v));
    }
    f32x4 du4;
    {
        ushort4 xcq = *(const ushort4*)&xcs[wave * 200 + lbase];
        du4 = d4 * f32x4{bf2f(xcq.x), bf2f(xcq.y), bf2f(xcq.z), bf2f(xcq.w)};
    }

    // pass 1: local affine transform per lane-chunk
    float P[DS], h[DS];
    #pragma unroll
    for (int n = 0; n < DS; n++) { P[n] = 1.f; h[n] = 0.f; }
    if (act) {
        #pragma unroll
        for (int n = 0; n < DS; n++) {
            float Avn = avs[wave][n];
            f32x4 Bn = *(const f32x4*)&sd[(12 + n) * 196 + lbase];
            float hn = 0.f, Pn = 1.f;
            #pragma unroll
            for (int s = 0; s < 4; s++) {
                float dA = __builtin_amdgcn_exp2f(d4[s] * Avn);
                hn = fmaf(hn, dA, du4[s] * Bn[s]);
                Pn *= dA;
            }
            P[n] = Pn; h[n] = hn;
        }
    }

    // Kogge-Stone inclusive scan of affine maps across lanes
    #pragma unroll
    for (int off = 1; off < 64; off <<= 1) {
        #pragma unroll
        for (int n = 0; n < DS; n++) {
            float Pp = __shfl_up(P[n], off);
            float Hp = __shfl_up(h[n], off);
            if (lane >= off) {
                h[n] = fmaf(P[n], Hp, h[n]);
                P[n] *= Pp;
            }
        }
    }
    #pragma unroll
    for (int n = 0; n < DS; n++) {  // exclusive: incoming state
        float Hp = __shfl_up(h[n], 1);
        h[n] = (lane == 0) ? 0.f : Hp;
    }

    // pass 2: replay with correct incoming state; y = h.C + xc*D, gate silu(z)
    if (act) {
        f32x4 acc4 = {0.f, 0.f, 0.f, 0.f};
        #pragma unroll
        for (int n = 0; n < DS; n++) {
            float Avn = avs[wave][n];
            f32x4 Bn = *(const f32x4*)&sd[(12 + n) * 196 + lbase];
            f32x4 Cn = *(const f32x4*)&sd[(28 + n) * 196 + lbase];
            float hn = h[n];
            #pragma unroll
            for (int s = 0; s < 4; s++) {
                float dA = __builtin_amdgcn_exp2f(d4[s] * Avn);
                hn = fmaf(hn, dA, du4[s] * Bn[s]);
                acc4[s] = fmaf(hn, Cn[s], acc4[s]);
            }
        }
        // re-read xc and z from LDS (kept out of the live range above)
        ushort4 xcq = *(const ushort4*)&xcs[wave * 200 + lbase];
        f32x4 xcv4 = {bf2f(xcq.x), bf2f(xcq.y), bf2f(xcq.z), bf2f(xcq.w)};
        ushort4 zq = *(const ushort4*)&zs[wave * 200 + lbase];
        f32x4 zv4 = {bf2f(zq.x), bf2f(zq.y), bf2f(zq.z), bf2f(zq.w)};
        const float Dv = Dp[e];
        ushort_t* yw = &ys[wave * 200 + lbase];
        #pragma unroll
        for (int s = 0; s < 4; s++) {
            float yv = fmaf(xcv4[s], Dv, acc4[s]);
            float zv = zv4[s];
            yw[s] = f2bf(yv * zv * sigmoidf_(zv));
        }
    }
    __syncthreads();
    if (tid < 196) {  // cooperative store of y for the 8 e's
        int l = tid;
        ushort4 o0, o1;
        o0.x = ys[0 * 200 + l]; o0.y = ys[1 * 200 + l];
        o0.z = ys[2 * 200 + l]; o0.w = ys[3 * 200 + l];
        o1.x = ys[4 * 200 + l]; o1.y = ys[5 * 200 + l];
        o1.z = ys[6 * 200 + l]; o1.w = ys[7 * 200 + l];
        ushort_t* yp = y + (size_t)(b * SEQL + l) * DI + eg * 8;
        *(ushort4*)yp = o0;
        *(ushort4*)(yp + 4) = o1;
    }
}

// ---------------- mean over L ----------------
__global__ void pool_kernel(const float* __restrict__ normed, float* __restrict__ pooled) {
    int b = blockIdx.x, d = threadIdx.x;
    float s = 0.f;
    for (int l = 0; l < SEQL; l++) s += normed[(size_t)(b * SEQL + l) * DM + d];
    pooled[b * DM + d] = s * (1.f / 196.f);
}

extern "C" void kernel_launch(void* const* d_in, const int* in_sizes, int n_in,
                              void* d_out, int out_size, void* d_ws, size_t ws_size,
                              hipStream_t stream) {
    const float* x       = (const float*)d_in[0];
    const float* patch_w = (const float*)d_in[1];
    const float* patch_b = (const float*)d_in[2];
    const float* norm_w  = (const float*)d_in[3];
    const float* norm_b  = (const float*)d_in[4];
    const float* in_w    = (const float*)d_in[5];
    const float* conv_w  = (const float*)d_in[6];
    const float* conv_b  = (const float*)d_in[7];
    const float* xp_w    = (const float*)d_in[8];
    const float* dt_w    = (const float*)d_in[9];
    const float* dt_b    = (const float*)d_in[10];
    const float* A_log   = (const float*)d_in[11];
    const float* Dp      = (const float*)d_in[12];
    const float* out_w   = (const float*)d_in[13];
    const float* normf_w = (const float*)d_in[14];
    const float* normf_b = (const float*)d_in[15];
    const float* head_w  = (const float*)d_in[16];
    const float* head_b  = (const float*)d_in[17];

    float* ws = (float*)d_ws;
    // Disjoint layout (only alias: x_bf over xcbf+y_bf, round-4-validated).
    float* residual     = ws;                          // [0, 2408448)
    float* hidden       = ws + 2408448;                // [2408448, 4816896)
    float* xz           = ws + 4816896;                // [4816896, 14450688)
    ushort_t* xcbf      = (ushort_t*)(ws + 14450688);  // [14450688, 16859136)
    ushort_t* y_bf      = (ushort_t*)(ws + 16859136);  // [16859136, 19267584)
    ushort_t* x_bf      = (ushort_t*)(ws + 14450688);  // alias, dead before layer-0 conv
    ushort_t* normed_bf = (ushort_t*)(ws + 19267584);  // [19267584, 20471808)
    float* xdbl_t       = ws + 20471808;               // [20471808, 21023744)
    float* pooled       = ws + 21023744;               // [21023744, 21036032)
    ushort_t* in_w_bf   = (ushort_t*)(ws + 21036032);  // [21036032, 22805504)
    ushort_t* out_w_bf  = (ushort_t*)(ws + 22805504);  // [22805504, 23690240)
    ushort_t* xp_w_bf   = (ushort_t*)(ws + 23690240);  // [23690240, 23985152)
    ushort_t* patch_w_bf= (ushort_t*)(ws + 23985152);  // [23985152, 24058880)
    // end 24,058,880 floats = 96.2 MB

    (void)hipMemsetAsync(residual, 0, (size_t)2408448 * sizeof(float), stream);

    f2bf4_kernel<<<3456, 256, 0, stream>>>(in_w, in_w_bf, 884736);
    f2bf4_kernel<<<1728, 256, 0, stream>>>(out_w, out_w_bf, 442368);
    f2bf4_kernel<<<144, 256, 0, stream>>>(patch_w, patch_w_bf, 36864);
    f2bf4_kernel<<<9408, 256, 0, stream>>>(x, x_bf, 2408448);
    xp_pad_kernel<<<2304, 256, 0, stream>>>(xp_w, xp_w_bf);

    gemm_patch_mfma<<<dim3(98, 3), 256, 0, stream>>>(x_bf, patch_w_bf, patch_b, hidden);

    for (int d = 0; d < DEPTH; ++d) {
        ln_kernel<true><<<3136, 256, 0, stream>>>(residual, hidden, norm_w + d * DM,
                                                  norm_b + d * DM, normed_bf);
        gemm_mfma<192, 2, 2, 12, false><<<dim3(98, 4), 256, 0, stream>>>(normed_bf,
                in_w_bf + (size_t)d * 768 * 192, xz, 192, 768);
        conv_silu_kernel<<<18816, 256, 0, stream>>>(xz, conv_w + d * DI * 4, conv_b + d * DI, xcbf);
        // x_proj -> transposed x_dbl [b][44][196]
        gemm_mfma<64, 4, 1, 3, true><<<dim3(98, 1), 256, 0, stream>>>(xcbf,
                xp_w_bf + (size_t)d * 64 * 384, xdbl_t, 384, 196);
        scan_kernel<<<dim3(64, 48), 512, 0, stream>>>(xdbl_t, xcbf, xz, dt_w + d * DI * DR,
                dt_b + d * DI, A_log + d * DI * DS, Dp + d * DI, y_bf);
        gemm_mfma<64, 4, 1, 4, false><<<dim3(98, 3), 256, 0, stream>>>(y_bf,
                out_w_bf + (size_t)d * 192 * 384, hidden, 384, 192);
    }

    ln_kernel<false><<<3136, 256, 0, stream>>>(residual, hidden, normf_w, normf_b, xz);
    pool_kernel<<<64, 192, 0, stream>>>(xz, pooled);
    gemm64<true><<<dim3(1, 16), 256, 0, stream>>>(pooled, head_w, head_b, (float*)d_out, 64, 1000, 192);
}